// Round 1
// 1051.187 us; speedup vs baseline: 1.2820x; 1.2820x over previous
//
#include <hip/hip_runtime.h>
#include <math.h>
#include <cstdint>

// ---------------- problem constants ----------------
#define NN     131072     // nodes
#define DDIM   128        // hidden dim
#define NHEAD  4
#define HDIM   32
#define NTYPE  3
#define NEDGE  262144     // edges per type (2^18)
#define NGRAPH 512
#define EPSV   1e-6f
#define SLOPEV 0.2f

typedef unsigned short bfraw;
typedef __attribute__((ext_vector_type(8))) short bf16x8;
typedef __attribute__((ext_vector_type(4))) float f32x4;

// ---------------- helpers ----------------
__device__ __forceinline__ float lrelu(float x){ return x >= 0.f ? x : SLOPEV*x; }
__device__ __forceinline__ float gelu_f(float x){ return 0.5f*x*(1.f+erff(x*0.70710678118654752f)); }
__device__ __forceinline__ bfraw f2bf(float f){
  unsigned int u = __float_as_uint(f);
  u += 0x7fffu + ((u >> 16) & 1u);          // RNE
  return (bfraw)(u >> 16);
}
__device__ __forceinline__ float4 ld_bf4(const bfraw* p){
  uint2 u = *reinterpret_cast<const uint2*>(p);
  float4 r;
  r.x = __uint_as_float(u.x << 16); r.y = __uint_as_float(u.x & 0xffff0000u);
  r.z = __uint_as_float(u.y << 16); r.w = __uint_as_float(u.y & 0xffff0000u);
  return r;
}

// ---------------- generic fill / convert ----------------
__global__ void fill_k(float* __restrict__ p, float v, int n){
  int i = blockIdx.x*blockDim.x + threadIdx.x;
  int stride = gridDim.x*blockDim.x;
  for (; i < n; i += stride) p[i] = v;
}

__global__ void conv_k(const float* __restrict__ in, bfraw* __restrict__ out, int n){
  int i = blockIdx.x*blockDim.x + threadIdx.x;
  int stride = gridDim.x*blockDim.x;
  for (; i < n; i += stride) out[i] = f2bf(in[i]);
}

// ---------------- CSR build (dst-sorted, per edge type) ----------------
__global__ void hist_k(const int* __restrict__ ei, int* __restrict__ deg){
  int idx = blockIdx.x*256 + threadIdx.x;          // < 3E
  int t = idx >> 18, e = idx & (NEDGE-1);
  int d = ei[(long)t*2*NEDGE + NEDGE + e];
  atomicAdd(&deg[t*NN + d], 1);
}

__global__ void scan_a_k(const int* __restrict__ deg, int* __restrict__ rp,
                         int* __restrict__ csum){
  __shared__ int sh[256];
  int t = blockIdx.y, chunk = blockIdx.x, tid = threadIdx.x;
  const int* dp = deg + (long)t*NN + chunk*2048 + tid*8;
  int v[8]; int s = 0;
  #pragma unroll
  for (int i=0;i<8;i++){ v[i] = dp[i]; s += v[i]; }
  sh[tid] = s; __syncthreads();
  for (int off=1; off<256; off<<=1){
    int x = (tid>=off) ? sh[tid-off] : 0;
    __syncthreads();
    sh[tid] += x;
    __syncthreads();
  }
  int run = sh[tid] - s;                            // exclusive prefix
  int* op = rp + (long)t*(NN+1) + chunk*2048 + tid*8;
  #pragma unroll
  for (int i=0;i<8;i++){ op[i] = run; run += v[i]; }
  if (tid == 255) csum[t*64 + chunk] = sh[255];
}

__global__ void scan_b_k(int* __restrict__ csum){
  __shared__ int sh[64];
  int t = blockIdx.x, tid = threadIdx.x;
  int s = csum[t*64 + tid];
  sh[tid] = s; __syncthreads();
  for (int off=1; off<64; off<<=1){
    int x = (tid>=off) ? sh[tid-off] : 0;
    __syncthreads();
    sh[tid] += x;
    __syncthreads();
  }
  csum[t*64 + tid] = sh[tid] - s;                   // exclusive
}

__global__ void scan_c_k(int* __restrict__ rp, const int* __restrict__ csum){
  int t = blockIdx.y, chunk = blockIdx.x, tid = threadIdx.x;
  int add = csum[t*64 + chunk];
  int* op = rp + (long)t*(NN+1) + chunk*2048 + tid*8;
  #pragma unroll
  for (int i=0;i<8;i++) op[i] += add;
  if (chunk == 63 && tid == 255) rp[(long)t*(NN+1) + NN] = NEDGE;
}

__global__ void scatter_k(const int* __restrict__ ei, const int* __restrict__ rp,
                          int* __restrict__ cnt, int* __restrict__ srcs){
  int idx = blockIdx.x*256 + threadIdx.x;          // < 3E
  int t = idx >> 18, e = idx & (NEDGE-1);
  int s = ei[(long)t*2*NEDGE + e];
  int d = ei[(long)t*2*NEDGE + NEDGE + e];
  int pos = rp[(long)t*(NN+1) + d] + atomicAdd(&cnt[t*NN + d], 1);
  srcs[(long)t*NEDGE + pos] = s;
}

// ---------------- weight swizzle: f32 [128,128] -> bf16 b-frag layout ----------------
// Wsw[((nt*4+kc)*64+lane)*8+j] = W[kc*32+(lane>>4)*8+j][nt*16+(lane&15)]
__global__ void wswz_k(const float* g0a, const float* g0b, const float* g0c,
                       const float* g1a, const float* g1b, const float* g1c,
                       const float* qw,
                       const float* wk, const float* wv,   // [3][128][128] each
                       const float* aw, const float* injw,
                       bfraw* __restrict__ Wall)
{
  int y = blockIdx.y;
  const float* src;
  switch(y){
    case 0: src = g0a; break;  case 1: src = g0b; break;  case 2: src = g0c; break;
    case 3: src = g1a; break;  case 4: src = g1b; break;  case 5: src = g1c; break;
    case 6: src = qw; break;
    case 7: case 8: case 9: src = wk + (long)(y-7)*16384; break;
    case 10: case 11: case 12: src = wv + (long)(y-10)*16384; break;
    case 13: src = aw; break;
    default: src = injw; break;
  }
  int i = blockIdx.x*256 + threadIdx.x;            // < 16384
  int j = i & 7, lane = (i>>3) & 63, kc = (i>>9) & 3, nt = i >> 11;
  int k = kc*32 + ((lane>>4)<<3) + j;
  int n = nt*16 + (lane & 15);
  Wall[(long)y*16384 + i] = f2bf(src[k*DDIM + n]);
}

// ---------------- GAT score projection, directly in swizzled b-frag layout ----------
// P[in, j] with j = t*8 + sd*4 + h  ==  sum_dd W_t[in, h*32+dd] * a_{sd}[t,h,dd]
// output: 4096 bf16 per layer (nt in {0,1}); cols >= 24 are zero.
__global__ void gatproj_k(const float* __restrict__ w, const float* __restrict__ asrc,
                          const float* __restrict__ adst, bfraw* __restrict__ out)
{
  int i = blockIdx.x*256 + threadIdx.x;            // < 4096
  int j = i & 7, lane = (i>>3) & 63, kc = (i>>9) & 3, nt = i >> 11;   // nt 0..1
  int k = kc*32 + ((lane>>4)<<3) + j;
  int n = nt*16 + (lane & 15);
  float s = 0.f;
  if (n < 24){
    int t = n >> 3, sd = (n >> 2) & 1, hh = n & 3;
    const float* a  = (sd ? adst : asrc) + ((long)t*NHEAD + hh)*HDIM;
    const float* wr = w + ((long)t*DDIM + k)*DDIM + hh*HDIM;
    #pragma unroll 8
    for (int dd=0; dd<HDIM; dd++) s += wr[dd]*a[dd];
  }
  out[i] = f2bf(s);
}

// ---------------- MFMA GEMM core: 128 rows x 128 cols per block, 4 waves -----------
__device__ __forceinline__ void gemm_core(const bfraw* __restrict__ A,
    const bfraw* __restrict__ Wsw, bfraw* Wl, int tid, long blockRow,
    f32x4 acc0[8], f32x4 acc1[8])
{
  #pragma unroll
  for (int i=0;i<8;i++)
    *reinterpret_cast<uint4*>(Wl + (i*256+tid)*8) =
        *reinterpret_cast<const uint4*>(Wsw + (i*256+tid)*8);
  __syncthreads();
  const int w = tid >> 6, lane = tid & 63;
  const long rowA = blockRow + w*32 + (lane & 15);
  const bfraw* A0 = A + rowA*DDIM + ((lane>>4)<<3);
  bf16x8 a0[4], a1[4];
  #pragma unroll
  for (int kc=0;kc<4;kc++){
    a0[kc] = *reinterpret_cast<const bf16x8*>(A0 + kc*32);
    a1[kc] = *reinterpret_cast<const bf16x8*>(A0 + 16*DDIM + kc*32);
  }
  const f32x4 zz = {0.f,0.f,0.f,0.f};
  #pragma unroll
  for (int nt=0;nt<8;nt++){ acc0[nt]=zz; acc1[nt]=zz; }
  #pragma unroll
  for (int nt=0;nt<8;nt++){
    #pragma unroll
    for (int kc=0;kc<4;kc++){
      bf16x8 b = *reinterpret_cast<const bf16x8*>(Wl + ((nt*4+kc)*64 + lane)*8);
      acc0[nt] = __builtin_amdgcn_mfma_f32_16x16x32_bf16(a0[kc], b, acc0[nt], 0, 0, 0);
      acc1[nt] = __builtin_amdgcn_mfma_f32_16x16x32_bf16(a1[kc], b, acc1[nt], 0, 0, 0);
    }
  }
}

__device__ __forceinline__ void gemm_store_bf16(f32x4 acc0[8], f32x4 acc1[8],
    const float* bias, bfraw* __restrict__ Cb, long blockRow, int tid)
{
  const int w = tid>>6, lane = tid&63, q = lane>>4;
  #pragma unroll
  for (int g=0; g<2; g++){
    #pragma unroll
    for (int nt=0;nt<8;nt++){
      int col = nt*16 + (lane & 15);
      float bv = bias ? bias[col] : 0.f;
      #pragma unroll
      for (int r=0;r<4;r++){
        long row = blockRow + w*32 + g*16 + q*4 + r;
        float v = (g ? acc1[nt][r] : acc0[nt][r]) + bv;
        Cb[row*DDIM + col] = f2bf(v);
      }
    }
  }
}

// generic GEMM: f32 out (Cf) or bf16 out (Cb), optional bias
__global__ __launch_bounds__(256) void gemm_out_k(
    const bfraw* __restrict__ A, const bfraw* __restrict__ Wsw,
    const float* __restrict__ bias, float* __restrict__ Cf, bfraw* __restrict__ Cb)
{
  __shared__ bfraw Wl[16384];
  f32x4 acc0[8], acc1[8];
  const long blockRow = (long)blockIdx.x * 128;
  gemm_core(A, Wsw, Wl, threadIdx.x, blockRow, acc0, acc1);
  if (Cf){
    const int tid = threadIdx.x, w = tid>>6, lane = tid&63, q = lane>>4;
    #pragma unroll
    for (int g=0; g<2; g++){
      #pragma unroll
      for (int nt=0;nt<8;nt++){
        int col = nt*16 + (lane & 15);
        float bv = bias ? bias[col] : 0.f;
        #pragma unroll
        for (int r=0;r<4;r++){
          long row = blockRow + w*32 + g*16 + q*4 + r;
          Cf[row*DDIM + col] = (g ? acc1[nt][r] : acc0[nt][r]) + bv;
        }
      }
    }
  } else {
    gemm_store_bf16(acc0, acc1, bias, Cb, blockRow, threadIdx.x);
  }
}

// 3 GEMMs (same A, 3 weights) in one launch via blockIdx.y, bf16 out
__global__ __launch_bounds__(256) void gemm3_k(
    const bfraw* __restrict__ A, const bfraw* __restrict__ Wbase,
    const float* __restrict__ biasBase,
    bfraw* __restrict__ O0, bfraw* __restrict__ O1, bfraw* __restrict__ O2)
{
  __shared__ bfraw Wl[16384];
  const int y = blockIdx.y;
  f32x4 acc0[8], acc1[8];
  const long blockRow = (long)blockIdx.x * 128;
  gemm_core(A, Wbase + (long)y*16384, Wl, threadIdx.x, blockRow, acc0, acc1);
  bfraw* Cb = (y==0) ? O0 : ((y==1) ? O1 : O2);
  const float* bias = biasBase ? biasBase + y*DDIM : nullptr;
  gemm_store_bf16(acc0, acc1, bias, Cb, blockRow, threadIdx.x);
}

// narrow GEMM: 24 GAT scores per node (cols 24..31 padded zero)
__global__ __launch_bounds__(256) void gemm_s24_k(
    const bfraw* __restrict__ A, const bfraw* __restrict__ Psw,
    float* __restrict__ SS)
{
  __shared__ bfraw Wl[4096];
  const int tid = threadIdx.x;
  #pragma unroll
  for (int i=0;i<2;i++)
    *reinterpret_cast<uint4*>(Wl + (i*256+tid)*8) =
        *reinterpret_cast<const uint4*>(Psw + (i*256+tid)*8);
  __syncthreads();
  const int w = tid >> 6, lane = tid & 63;
  const long blockRow = (long)blockIdx.x * 128;
  const long rowA = blockRow + w*32 + (lane & 15);
  const bfraw* A0 = A + rowA*DDIM + ((lane>>4)<<3);
  bf16x8 a0[4], a1[4];
  #pragma unroll
  for (int kc=0;kc<4;kc++){
    a0[kc] = *reinterpret_cast<const bf16x8*>(A0 + kc*32);
    a1[kc] = *reinterpret_cast<const bf16x8*>(A0 + 16*DDIM + kc*32);
  }
  const f32x4 zz = {0.f,0.f,0.f,0.f};
  f32x4 acc0[2], acc1[2];
  #pragma unroll
  for (int nt=0;nt<2;nt++){ acc0[nt]=zz; acc1[nt]=zz; }
  #pragma unroll
  for (int nt=0;nt<2;nt++){
    #pragma unroll
    for (int kc=0;kc<4;kc++){
      bf16x8 b = *reinterpret_cast<const bf16x8*>(Wl + ((nt*4+kc)*64 + lane)*8);
      acc0[nt] = __builtin_amdgcn_mfma_f32_16x16x32_bf16(a0[kc], b, acc0[nt], 0, 0, 0);
      acc1[nt] = __builtin_amdgcn_mfma_f32_16x16x32_bf16(a1[kc], b, acc1[nt], 0, 0, 0);
    }
  }
  const int q = lane >> 4;
  #pragma unroll
  for (int g=0; g<2; g++){
    #pragma unroll
    for (int nt=0;nt<2;nt++){
      int col = nt*16 + (lane & 15);
      if (col < 24){
        #pragma unroll
        for (int r=0;r<4;r++){
          long row = blockRow + w*32 + g*16 + q*4 + r;
          SS[row*24 + col] = (g ? acc1[nt][r] : acc0[nt][r]);
        }
      }
    }
  }
}

// GEMM + res3 epilogue: v = g*out + (1-g)*x2; x3 = lrelu(x2 + norm*rms(v)); X in-place
__global__ __launch_bounds__(256) void gemm_res3_k(
    const bfraw* __restrict__ A, const bfraw* __restrict__ Wsw,
    const float* __restrict__ bias, float* __restrict__ X,
    const float* __restrict__ norm, const float* __restrict__ skip)
{
  __shared__ bfraw Wl[16384];
  f32x4 acc0[8], acc1[8];
  const long blockRow = (long)blockIdx.x * 128;
  gemm_core(A, Wsw, Wl, threadIdx.x, blockRow, acc0, acc1);
  const int tid = threadIdx.x, w = tid>>6, lane = tid&63, q = lane>>4;
  const float gsk = 1.f/(1.f + __expf(-skip[0]));
  #pragma unroll
  for (int g=0; g<2; g++){
    #pragma unroll
    for (int r=0;r<4;r++){
      long row = blockRow + w*32 + g*16 + q*4 + r;
      float vv[8], xx[8];
      float sq = 0.f;
      #pragma unroll
      for (int nt=0;nt<8;nt++){
        int col = nt*16 + (lane & 15);
        float o  = (g ? acc1[nt][r] : acc0[nt][r]) + bias[col];
        float xo = X[row*DDIM + col];
        float v  = gsk*o + (1.f-gsk)*xo;
        vv[nt] = v; xx[nt] = xo; sq += v*v;
      }
      sq += __shfl_xor(sq, 1, 64);
      sq += __shfl_xor(sq, 2, 64);
      sq += __shfl_xor(sq, 4, 64);
      sq += __shfl_xor(sq, 8, 64);
      float rr = rsqrtf(sq*(1.f/DDIM) + EPSV);
      #pragma unroll
      for (int nt=0;nt<8;nt++){
        int col = nt*16 + (lane & 15);
        X[row*DDIM + col] = lrelu(xx[nt] + norm[col]*vv[nt]*rr);
      }
    }
  }
}

// GEMM + FiLM epilogue: out = (1+gamma')*(acc+bias+x3) + beta'  (gbt pre-tanh'd)
__global__ __launch_bounds__(256) void gemm_film_k(
    const bfraw* __restrict__ A, const bfraw* __restrict__ Wsw,
    const float* __restrict__ bias, const float* __restrict__ Xadd,
    const float* __restrict__ gbt, float* __restrict__ out)
{
  __shared__ bfraw Wl[16384];
  f32x4 acc0[8], acc1[8];
  const long blockRow = (long)blockIdx.x * 128;
  gemm_core(A, Wsw, Wl, threadIdx.x, blockRow, acc0, acc1);
  const int tid = threadIdx.x, w = tid>>6, lane = tid&63, q = lane>>4;
  #pragma unroll
  for (int g=0; g<2; g++){
    #pragma unroll
    for (int nt=0;nt<8;nt++){
      int col = nt*16 + (lane & 15);
      float bv = bias[col];
      #pragma unroll
      for (int r=0;r<4;r++){
        long row = blockRow + w*32 + g*16 + q*4 + r;
        long gi  = row >> 8;                              // 256 nodes per graph
        float v  = (g ? acc1[nt][r] : acc0[nt][r]) + bv + Xadd[row*DDIM + col];
        float ga = gbt[gi*256 + col];
        float be = gbt[gi*256 + 128 + col];
        out[row*DDIM + col] = (1.f + ga)*v + be;
      }
    }
  }
}

// ---------------- fused GAT: 3-type online-softmax agg + bias + RMS + residual ------
__global__ __launch_bounds__(256) void gat_fused_k(
    const int* __restrict__ rp, const int* __restrict__ srcs,
    const bfraw* __restrict__ H0, const bfraw* __restrict__ H1,
    const bfraw* __restrict__ H2, const float* __restrict__ SS,
    const float* __restrict__ gatb, const float* __restrict__ xold,
    const float* __restrict__ norm, float* __restrict__ X, bfraw* __restrict__ Xb)
{
  int node = blockIdx.x*8 + (threadIdx.x >> 5);
  int l = threadIdx.x & 31;
  int hd = l >> 3;
  const bfraw* Hs[3] = {H0, H1, H2};
  float tx=0.f, ty=0.f, tz=0.f, tw=0.f;
  #pragma unroll
  for (int t=0; t<3; t++){
    const bfraw* Ht = Hs[t];
    float dsv = SS[(long)node*24 + t*8 + 4 + hd];
    float m = lrelu(SS[(long)node*24 + t*8 + hd] + dsv);   // self-loop seeds state
    float lsum = 1.f;
    float4 a4 = ld_bf4(Ht + (long)node*DDIM + l*4);
    int beg = rp[t*(NN+1) + node], end = rp[t*(NN+1) + node + 1];
    const int* sp = srcs + (long)t*NEDGE;
    for (int p=beg; p<end; p++){
      int s = sp[p];
      float a = lrelu(SS[(long)s*24 + t*8 + hd] + dsv);
      float4 hv = ld_bf4(Ht + (long)s*DDIM + l*4);
      float mn = fmaxf(m, a);
      float wo = __expf(m - mn);
      float wn = __expf(a - mn);
      lsum = lsum*wo + wn;
      a4.x = a4.x*wo + wn*hv.x;
      a4.y = a4.y*wo + wn*hv.y;
      a4.z = a4.z*wo + wn*hv.z;
      a4.w = a4.w*wo + wn*hv.w;
      m = mn;
    }
    float inv = 1.f/lsum;
    tx += a4.x*inv; ty += a4.y*inv; tz += a4.z*inv; tw += a4.w*inv;
  }
  int f = l*4;
  tx += gatb[f]   + gatb[DDIM+f]   + gatb[2*DDIM+f];
  ty += gatb[f+1] + gatb[DDIM+f+1] + gatb[2*DDIM+f+1];
  tz += gatb[f+2] + gatb[DDIM+f+2] + gatb[2*DDIM+f+2];
  tw += gatb[f+3] + gatb[DDIM+f+3] + gatb[2*DDIM+f+3];
  float sq = tx*tx + ty*ty + tz*tz + tw*tw;
  sq += __shfl_xor(sq, 1, 64);
  sq += __shfl_xor(sq, 2, 64);
  sq += __shfl_xor(sq, 4, 64);
  sq += __shfl_xor(sq, 8, 64);
  sq += __shfl_xor(sq, 16, 64);
  float r = rsqrtf(sq*(1.f/DDIM) + EPSV);
  float4 x4 = *reinterpret_cast<const float4*>(xold + (long)node*DDIM + f);
  float4 o;
  o.x = lrelu(x4.x + norm[f]  *tx*r);
  o.y = lrelu(x4.y + norm[f+1]*ty*r);
  o.z = lrelu(x4.z + norm[f+2]*tz*r);
  o.w = lrelu(x4.w + norm[f+3]*tw*r);
  *reinterpret_cast<float4*>(X + (long)node*DDIM + f) = o;
  unsigned int lo = ((unsigned int)f2bf(o.y) << 16) | f2bf(o.x);
  unsigned int hi = ((unsigned int)f2bf(o.w) << 16) | f2bf(o.z);
  *reinterpret_cast<uint2*>(Xb + (long)node*DDIM + f) = make_uint2(lo, hi);
}

// ---------------- HGT: fold rel into projection ----------------
__global__ void fold_k(const float* __restrict__ w, const float* __restrict__ b,
                       const float* __restrict__ rel, float* __restrict__ Weff,
                       float* __restrict__ beff)
{
  int idx = blockIdx.x*256 + threadIdx.x;
  if (idx >= NTYPE*DDIM*DDIM) return;
  int he = idx & 127, c = (idx >> 7) & 127, t = idx >> 14;
  int h = he >> 5, e = he & 31;
  const float* wrow = w + (long)c*DDIM + h*HDIM;
  const float* relm = rel + ((long)(t*NHEAD + h)*HDIM)*HDIM + e;
  float s = 0.f;
  #pragma unroll 8
  for (int d=0; d<HDIM; d++) s += wrow[d] * relm[d*HDIM];
  Weff[(long)t*DDIM*DDIM + (long)c*DDIM + he] = s;
  if (c == 0){
    float sb = 0.f;
    #pragma unroll 8
    for (int d=0; d<HDIM; d++) sb += b[h*HDIM+d] * relm[d*HDIM];
    beff[(long)t*DDIM + he] = sb;
  }
}

// ---------------- HGT phase A: scores + carried per-node max (per type) -------------
__global__ __launch_bounds__(256) void hgt_score_pass_k(
    const int* __restrict__ rp, const int* __restrict__ srcs,
    const float* __restrict__ q, const bfraw* __restrict__ kt,
    const float* __restrict__ relp, float* __restrict__ S,
    float* __restrict__ mbuf, int initFlag)
{
  int node = blockIdx.x*8 + (threadIdx.x >> 5);
  int l = threadIdx.x & 31;
  int hd = l >> 3, sub = l & 7;
  float4 qv = *reinterpret_cast<const float4*>(q + (long)node*DDIM + l*4);
  int beg = rp[node], end = rp[node+1];
  float m = initFlag ? -INFINITY : mbuf[(long)node*4 + hd];
  float scale = relp[hd] * 0.17677669529663687f;   // 1/sqrt(32)
  for (int p=beg; p<end; p++){
    int s = srcs[p];
    float4 kv = ld_bf4(kt + (long)s*DDIM + l*4);
    float dot = qv.x*kv.x + qv.y*kv.y + qv.z*kv.z + qv.w*kv.w;
    dot += __shfl_xor(dot, 1, 64);
    dot += __shfl_xor(dot, 2, 64);
    dot += __shfl_xor(dot, 4, 64);
    float sc = dot * scale;
    if (sub == 0) S[(long)p*4 + hd] = sc;
    m = fmaxf(m, sc);
  }
  if (sub == 0) mbuf[(long)node*4 + hd] = m;
}

// ---------------- HGT fused acc: 3 types, registers only, gelu finalize -> bf16 -----
__global__ __launch_bounds__(256) void hgt_acc_fused_k(
    const int* __restrict__ rp, const int* __restrict__ srcs,
    const float* __restrict__ S, const bfraw* __restrict__ V0,
    const bfraw* __restrict__ V1, const bfraw* __restrict__ V2,
    const float* __restrict__ mbuf, bfraw* __restrict__ out)
{
  int node = blockIdx.x*8 + (threadIdx.x >> 5);
  int l = threadIdx.x & 31;
  int hd = l >> 3;
  float m = mbuf[(long)node*4 + hd];
  float ax=0.f, ay=0.f, az=0.f, aw=0.f, lsum=0.f;
  const bfraw* Vs[3] = {V0, V1, V2};
  #pragma unroll
  for (int t=0; t<3; t++){
    const bfraw* Vt = Vs[t];
    const float* Sp = S + (long)t*NEDGE*4;
    const int* sp = srcs + (long)t*NEDGE;
    int beg = rp[t*(NN+1) + node], end = rp[t*(NN+1) + node + 1];
    for (int p=beg; p<end; p++){
      int s = sp[p];
      float ex = __expf(Sp[(long)p*4 + hd] - m);
      float4 vv = ld_bf4(Vt + (long)s*DDIM + l*4);
      ax += ex*vv.x; ay += ex*vv.y; az += ex*vv.z; aw += ex*vv.w;
      lsum += ex;
    }
  }
  float inv = (lsum > 0.f) ? 1.f/lsum : 0.f;
  float o0 = gelu_f(ax*inv), o1 = gelu_f(ay*inv);
  float o2 = gelu_f(az*inv), o3 = gelu_f(aw*inv);
  unsigned int lo = ((unsigned int)f2bf(o1) << 16) | f2bf(o0);
  unsigned int hi = ((unsigned int)f2bf(o3) << 16) | f2bf(o2);
  *reinterpret_cast<uint2*>(out + (long)node*DDIM + l*4) = make_uint2(lo, hi);
}

// ---------------- FiLM ----------------
__global__ void film1_k(const float* __restrict__ z, const float* __restrict__ w1,
                        const float* __restrict__ b1, float* __restrict__ f1)
{
  int idx = blockIdx.x*256 + threadIdx.x;
  if (idx >= NGRAPH*256) return;
  int j = idx & 255, b = idx >> 8;
  const float* zr = z + (long)b*DDIM;
  float s = b1[j];
  for (int k=0;k<DDIM;k++) s += zr[k] * w1[(long)k*256 + j];
  f1[idx] = gelu_f(s);
}

__global__ void film2_k(const float* __restrict__ f1, const float* __restrict__ w2,
                        const float* __restrict__ b2, float* __restrict__ gb)
{
  int idx = blockIdx.x*256 + threadIdx.x;
  if (idx >= NGRAPH*256) return;
  int j = idx & 255, b = idx >> 8;
  const float* fr = f1 + (long)b*256;
  float s = b2[j];
  for (int k=0;k<256;k++) s += fr[k] * w2[(long)k*256 + j];
  gb[idx] = 0.1f*tanhf(s);                       // pre-apply 0.1*tanh for epilogue
}

// ---------------- host ----------------
extern "C" void kernel_launch(void* const* d_in, const int* in_sizes, int n_in,
                              void* d_out, int out_size, void* d_ws, size_t ws_size,
                              hipStream_t stream)
{
  (void)in_sizes; (void)n_in; (void)out_size; (void)ws_size;
  const float* x_cell = (const float*)d_in[0];
  const float* x_emb  = (const float*)d_in[1];
  const float* z_h    = (const float*)d_in[2];
  const int*   ei     = (const int*)d_in[3];
  const float* gw[2]  = {(const float*)d_in[4],  (const float*)d_in[8]};
  const float* gas[2] = {(const float*)d_in[5],  (const float*)d_in[9]};
  const float* gad[2] = {(const float*)d_in[6],  (const float*)d_in[10]};
  const float* gbi[2] = {(const float*)d_in[7],  (const float*)d_in[11]};
  const float* norm1  = (const float*)d_in[12];
  const float* norm2  = (const float*)d_in[13];
  const float* norm3  = (const float*)d_in[14];
  const float* kw = (const float*)d_in[15]; const float* kb = (const float*)d_in[16];
  const float* qw = (const float*)d_in[17]; const float* qb = (const float*)d_in[18];
  const float* vw = (const float*)d_in[19]; const float* vb = (const float*)d_in[20];
  const float* relk = (const float*)d_in[21];
  const float* relv = (const float*)d_in[22];
  const float* relp = (const float*)d_in[23];
  const float* aw = (const float*)d_in[24]; const float* ab = (const float*)d_in[25];
  const float* skip = (const float*)d_in[26];
  const float* injw = (const float*)d_in[27]; const float* injb = (const float*)d_in[28];
  const float* fw1 = (const float*)d_in[29]; const float* fb1 = (const float*)d_in[30];
  const float* fw2 = (const float*)d_in[31]; const float* fb2 = (const float*)d_in[32];

  const long ND = (long)NN*DDIM;
  float* X    = (float*)d_ws;                    // x1 / x2 / x3 (f32)
  float* K    = X + ND;                          // q f32 | 2x bf16 (H1/H2, V1/V2)
  bfraw* Xb   = (bfraw*)(K + ND);                // bf16 GEMM A; later HGT attn out
  bfraw* Hb   = Xb + ND;                         // bf16: h0 / kt / vt0 / x_emb
  float* Sbuf = (float*)(Hb + ND);               // GAT SS [N][24] | HGT S [3E][4]
  float* sA   = Sbuf + (long)NTYPE*NEDGE*4;      // HGT m
  float* sB   = sA + (long)NN*4;                 // (spare)
  float* WkE  = sB + (long)NN*4;
  float* bkE  = WkE + (long)NTYPE*DDIM*DDIM;
  float* WvE  = bkE + (long)NTYPE*DDIM;
  float* bvE  = WvE + (long)NTYPE*DDIM*DDIM;
  bfraw* Pswz = (bfraw*)(bvE + (long)NTYPE*DDIM);   // 2 layers x 4096 bf16
  bfraw* Wall = Pswz + (long)2*4096;                // 15 swizzled bf16 weights
  float* f1b  = (float*)(Wall + (long)15*16384);
  float* gbb  = f1b + (long)NGRAPH*256;
  int*   deg  = (int*)(gbb + (long)NGRAPH*256);  // 3N (reused as cnt)
  int*   rp   = deg + (long)NTYPE*NN;            // 3(N+1)
  int*   srcs = rp  + (long)NTYPE*(NN+1);        // 3E
  int*   csum = srcs + (long)NTYPE*NEDGE;        // 192

  bfraw* H1 = (bfraw*)K;                         // K reused as 2 bf16 buffers
  bfraw* H2 = ((bfraw*)K) + ND;

  const dim3 b256(256);
  float* NF = nullptr; bfraw* NB = nullptr;

  // ---------- CSR build ----------
  fill_k<<<256, b256, 0, stream>>>((float*)deg, 0.f, NTYPE*NN);
  hist_k<<<(NTYPE*NEDGE)/256, b256, 0, stream>>>(ei, deg);
  scan_a_k<<<dim3(64, NTYPE), b256, 0, stream>>>(deg, rp, csum);
  scan_b_k<<<NTYPE, 64, 0, stream>>>(csum);
  scan_c_k<<<dim3(64, NTYPE), b256, 0, stream>>>(rp, csum);
  fill_k<<<256, b256, 0, stream>>>((float*)deg, 0.f, NTYPE*NN);   // cnt
  scatter_k<<<(NTYPE*NEDGE)/256, b256, 0, stream>>>(ei, rp, deg, srcs);

  // ---------- weight prep ----------
  fold_k<<<(NTYPE*DDIM*DDIM)/256, b256, 0, stream>>>(kw, kb, relk, WkE, bkE);
  fold_k<<<(NTYPE*DDIM*DDIM)/256, b256, 0, stream>>>(vw, vb, relv, WvE, bvE);
  wswz_k<<<dim3(64, 15), b256, 0, stream>>>(
      gw[0], gw[0]+16384, gw[0]+32768,
      gw[1], gw[1]+16384, gw[1]+32768,
      qw, WkE, WvE, aw, injw, Wall);
  gatproj_k<<<16, b256, 0, stream>>>(gw[0], gas[0], gad[0], Pswz);
  gatproj_k<<<16, b256, 0, stream>>>(gw[1], gas[1], gad[1], Pswz + 4096);

  // ---------- FiLM (independent, run early) ----------
  film1_k<<<(NGRAPH*256)/256, b256, 0, stream>>>(z_h, fw1, fb1, f1b);
  film2_k<<<(NGRAPH*256)/256, b256, 0, stream>>>(f1b, fw2, fb2, gbb);

  // ---------- GAT layers ----------
  conv_k<<<2048, b256, 0, stream>>>(x_cell, Xb, (int)ND);
  for (int layer=0; layer<2; layer++){
    gemm_s24_k<<<NN/128, b256, 0, stream>>>(Xb, Pswz + (long)layer*4096, Sbuf);
    gemm3_k<<<dim3(NN/128, 3), b256, 0, stream>>>(
        Xb, Wall + (long)layer*3*16384, NF, Hb, H1, H2);
    gat_fused_k<<<NN/8, b256, 0, stream>>>(
        rp, srcs, Hb, H1, H2, Sbuf, gbi[layer],
        (layer==0) ? x_cell : X, (layer==0) ? norm1 : norm2, X, Xb);
  }

  // ---------- HGT ----------
  gemm_out_k<<<NN/128, b256, 0, stream>>>(Xb, Wall + (long)6*16384, qb, K, NB);  // q f32
  for (int t=0; t<NTYPE; t++){
    gemm_out_k<<<NN/128, b256, 0, stream>>>(
        Xb, Wall + (long)(7+t)*16384, bkE + t*DDIM, NF, Hb);                     // kt
    hgt_score_pass_k<<<NN/8, b256, 0, stream>>>(rp + (long)t*(NN+1), srcs + (long)t*NEDGE,
        K, Hb, relp + t*NHEAD, Sbuf + (long)t*NEDGE*4, sA, t==0);
  }
  gemm3_k<<<dim3(NN/128, 3), b256, 0, stream>>>(
      Xb, Wall + (long)10*16384, bvE, Hb, H1, H2);                               // vt0..2
  hgt_acc_fused_k<<<NN/8, b256, 0, stream>>>(rp, srcs, Sbuf, Hb, H1, H2, sA, Xb);
  gemm_res3_k<<<NN/128, b256, 0, stream>>>(Xb, Wall + (long)13*16384, ab,
                                           X, norm3, skip);                      // x3 in X
  conv_k<<<2048, b256, 0, stream>>>(x_emb, Hb, (int)ND);
  gemm_film_k<<<NN/128, b256, 0, stream>>>(Hb, Wall + (long)14*16384, injb,
                                           X, gbb, (float*)d_out);
}

// Round 2
// 962.609 us; speedup vs baseline: 1.4000x; 1.0920x over previous
//
#include <hip/hip_runtime.h>
#include <math.h>
#include <cstdint>

// ---------------- problem constants ----------------
#define NN     131072     // nodes
#define DDIM   128        // hidden dim
#define NHEAD  4
#define HDIM   32
#define NTYPE  3
#define NEDGE  262144     // edges per type (2^18)
#define NGRAPH 512
#define EPSV   1e-6f
#define SLOPEV 0.2f

typedef unsigned short bfraw;
typedef __attribute__((ext_vector_type(8))) short bf16x8;
typedef __attribute__((ext_vector_type(4))) float f32x4;

// ---------------- helpers ----------------
__device__ __forceinline__ float lrelu(float x){ return x >= 0.f ? x : SLOPEV*x; }
__device__ __forceinline__ float gelu_f(float x){ return 0.5f*x*(1.f+erff(x*0.70710678118654752f)); }
__device__ __forceinline__ bfraw f2bf(float f){
  unsigned int u = __float_as_uint(f);
  u += 0x7fffu + ((u >> 16) & 1u);          // RNE
  return (bfraw)(u >> 16);
}
__device__ __forceinline__ float4 ld_bf4(const bfraw* p){
  uint2 u = *reinterpret_cast<const uint2*>(p);
  float4 r;
  r.x = __uint_as_float(u.x << 16); r.y = __uint_as_float(u.x & 0xffff0000u);
  r.z = __uint_as_float(u.y << 16); r.w = __uint_as_float(u.y & 0xffff0000u);
  return r;
}
__device__ __forceinline__ bf16x8 pack_bf8(const float* p){
  float4 u = *reinterpret_cast<const float4*>(p);
  float4 v = *reinterpret_cast<const float4*>(p+4);
  bf16x8 r;
  r[0]=(short)f2bf(u.x); r[1]=(short)f2bf(u.y); r[2]=(short)f2bf(u.z); r[3]=(short)f2bf(u.w);
  r[4]=(short)f2bf(v.x); r[5]=(short)f2bf(v.y); r[6]=(short)f2bf(v.z); r[7]=(short)f2bf(v.w);
  return r;
}

// ---------------- generic fill / convert ----------------
__global__ void fill_k(float* __restrict__ p, float v, int n){
  int i = blockIdx.x*blockDim.x + threadIdx.x;
  int stride = gridDim.x*blockDim.x;
  for (; i < n; i += stride) p[i] = v;
}

__global__ void conv_k(const float* __restrict__ in, bfraw* __restrict__ out, int n){
  int i = blockIdx.x*blockDim.x + threadIdx.x;
  int stride = gridDim.x*blockDim.x;
  for (; i < n; i += stride) out[i] = f2bf(in[i]);
}

// ---------------- CSR build (dst-sorted, per edge type) ----------------
__global__ void hist_k(const int* __restrict__ ei, int* __restrict__ deg){
  int idx = blockIdx.x*256 + threadIdx.x;          // < 3E
  int t = idx >> 18, e = idx & (NEDGE-1);
  int d = ei[(long)t*2*NEDGE + NEDGE + e];
  atomicAdd(&deg[t*NN + d], 1);
}

__global__ void scan_a_k(const int* __restrict__ deg, int* __restrict__ rp,
                         int* __restrict__ csum){
  __shared__ int sh[256];
  int t = blockIdx.y, chunk = blockIdx.x, tid = threadIdx.x;
  const int* dp = deg + (long)t*NN + chunk*2048 + tid*8;
  int v[8]; int s = 0;
  #pragma unroll
  for (int i=0;i<8;i++){ v[i] = dp[i]; s += v[i]; }
  sh[tid] = s; __syncthreads();
  for (int off=1; off<256; off<<=1){
    int x = (tid>=off) ? sh[tid-off] : 0;
    __syncthreads();
    sh[tid] += x;
    __syncthreads();
  }
  int run = sh[tid] - s;                            // exclusive prefix
  int* op = rp + (long)t*(NN+1) + chunk*2048 + tid*8;
  #pragma unroll
  for (int i=0;i<8;i++){ op[i] = run; run += v[i]; }
  if (tid == 255) csum[t*64 + chunk] = sh[255];
}

__global__ void scan_b_k(int* __restrict__ csum){
  __shared__ int sh[64];
  int t = blockIdx.x, tid = threadIdx.x;
  int s = csum[t*64 + tid];
  sh[tid] = s; __syncthreads();
  for (int off=1; off<64; off<<=1){
    int x = (tid>=off) ? sh[tid-off] : 0;
    __syncthreads();
    sh[tid] += x;
    __syncthreads();
  }
  csum[t*64 + tid] = sh[tid] - s;                   // exclusive
}

__global__ void scan_c_k(int* __restrict__ rp, const int* __restrict__ csum){
  int t = blockIdx.y, chunk = blockIdx.x, tid = threadIdx.x;
  int add = csum[t*64 + chunk];
  int* op = rp + (long)t*(NN+1) + chunk*2048 + tid*8;
  #pragma unroll
  for (int i=0;i<8;i++) op[i] += add;
  if (chunk == 63 && tid == 255) rp[(long)t*(NN+1) + NN] = NEDGE;
}

__global__ void scatter_k(const int* __restrict__ ei, const int* __restrict__ rp,
                          int* __restrict__ cnt, int* __restrict__ srcs){
  int idx = blockIdx.x*256 + threadIdx.x;          // < 3E
  int t = idx >> 18, e = idx & (NEDGE-1);
  int s = ei[(long)t*2*NEDGE + e];
  int d = ei[(long)t*2*NEDGE + NEDGE + e];
  int pos = rp[(long)t*(NN+1) + d] + atomicAdd(&cnt[t*NN + d], 1);
  srcs[(long)t*NEDGE + pos] = s;
}

// ---------------- weight swizzle: f32 [128,128] -> bf16 b-frag layout ----------------
// Wsw[((nt*4+kc)*64+lane)*8+j] = W[kc*32+(lane>>4)*8+j][nt*16+(lane&15)]
__global__ void wswz_k(const float* g0a, const float* g0b, const float* g0c,
                       const float* g1a, const float* g1b, const float* g1c,
                       const float* qw,
                       const float* wk, const float* wv,   // [3][128][128] each
                       const float* aw, const float* injw,
                       bfraw* __restrict__ Wall)
{
  int y = blockIdx.y;
  const float* src;
  switch(y){
    case 0: src = g0a; break;  case 1: src = g0b; break;  case 2: src = g0c; break;
    case 3: src = g1a; break;  case 4: src = g1b; break;  case 5: src = g1c; break;
    case 6: src = qw; break;
    case 7: case 8: case 9: src = wk + (long)(y-7)*16384; break;
    case 10: case 11: case 12: src = wv + (long)(y-10)*16384; break;
    case 13: src = aw; break;
    default: src = injw; break;
  }
  int i = blockIdx.x*256 + threadIdx.x;            // < 16384
  int j = i & 7, lane = (i>>3) & 63, kc = (i>>9) & 3, nt = i >> 11;
  int k = kc*32 + ((lane>>4)<<3) + j;
  int n = nt*16 + (lane & 15);
  Wall[(long)y*16384 + i] = f2bf(src[k*DDIM + n]);
}

// ---------------- GAT score projection, directly in swizzled b-frag layout ----------
// P[in, j] with j = t*8 + sd*4 + h  ==  sum_dd W_t[in, h*32+dd] * a_{sd}[t,h,dd]
// output: 4096 bf16 per layer (nt in {0,1}); cols >= 24 are zero.
__global__ void gatproj_k(const float* __restrict__ w, const float* __restrict__ asrc,
                          const float* __restrict__ adst, bfraw* __restrict__ out)
{
  int i = blockIdx.x*256 + threadIdx.x;            // < 4096
  int j = i & 7, lane = (i>>3) & 63, kc = (i>>9) & 3, nt = i >> 11;   // nt 0..1
  int k = kc*32 + ((lane>>4)<<3) + j;
  int n = nt*16 + (lane & 15);
  float s = 0.f;
  if (n < 24){
    int t = n >> 3, sd = (n >> 2) & 1, hh = n & 3;
    const float* a  = (sd ? adst : asrc) + ((long)t*NHEAD + hh)*HDIM;
    const float* wr = w + ((long)t*DDIM + k)*DDIM + hh*HDIM;
    #pragma unroll 8
    for (int dd=0; dd<HDIM; dd++) s += wr[dd]*a[dd];
  }
  out[i] = f2bf(s);
}

// ---------------- MFMA GEMM building blocks -----------------------------------------
__device__ __forceinline__ void load_afrags_bf16(const bfraw* __restrict__ A,
    long blockRow, int tid, bf16x8 a0[4], bf16x8 a1[4])
{
  const int w = tid >> 6, lane = tid & 63;
  const long rowA = blockRow + w*32 + (lane & 15);
  const bfraw* A0 = A + rowA*DDIM + ((lane>>4)<<3);
  #pragma unroll
  for (int kc=0;kc<4;kc++){
    a0[kc] = *reinterpret_cast<const bf16x8*>(A0 + kc*32);
    a1[kc] = *reinterpret_cast<const bf16x8*>(A0 + 16*DDIM + kc*32);
  }
}

__device__ __forceinline__ void load_afrags_f32(const float* __restrict__ A,
    long blockRow, int tid, bf16x8 a0[4], bf16x8 a1[4])
{
  const int w = tid >> 6, lane = tid & 63;
  const long rowA = blockRow + w*32 + (lane & 15);
  const float* A0 = A + rowA*DDIM + ((lane>>4)<<3);
  #pragma unroll
  for (int kc=0;kc<4;kc++){
    a0[kc] = pack_bf8(A0 + kc*32);
    a1[kc] = pack_bf8(A0 + 16*DDIM + kc*32);
  }
}

__device__ __forceinline__ void mfma_128(const bfraw* Wl, int lane,
    bf16x8 a0[4], bf16x8 a1[4], f32x4 acc0[8], f32x4 acc1[8])
{
  const f32x4 zz = {0.f,0.f,0.f,0.f};
  #pragma unroll
  for (int nt=0;nt<8;nt++){ acc0[nt]=zz; acc1[nt]=zz; }
  #pragma unroll
  for (int nt=0;nt<8;nt++){
    #pragma unroll
    for (int kc=0;kc<4;kc++){
      bf16x8 b = *reinterpret_cast<const bf16x8*>(Wl + ((nt*4+kc)*64 + lane)*8);
      acc0[nt] = __builtin_amdgcn_mfma_f32_16x16x32_bf16(a0[kc], b, acc0[nt], 0, 0, 0);
      acc1[nt] = __builtin_amdgcn_mfma_f32_16x16x32_bf16(a1[kc], b, acc1[nt], 0, 0, 0);
    }
  }
}

__device__ __forceinline__ void gemm_store_bf16(f32x4 acc0[8], f32x4 acc1[8],
    const float* bias, bfraw* __restrict__ Cb, long blockRow, int tid)
{
  const int w = tid>>6, lane = tid&63, q = lane>>4;
  #pragma unroll
  for (int g=0; g<2; g++){
    #pragma unroll
    for (int nt=0;nt<8;nt++){
      int col = nt*16 + (lane & 15);
      float bv = bias ? bias[col] : 0.f;
      #pragma unroll
      for (int r=0;r<4;r++){
        long row = blockRow + w*32 + g*16 + q*4 + r;
        float v = (g ? acc1[nt][r] : acc0[nt][r]) + bv;
        Cb[row*DDIM + col] = f2bf(v);
      }
    }
  }
}

// generic single GEMM: bf16 out, optional bias
__global__ __launch_bounds__(256) void gemm_out_k(
    const bfraw* __restrict__ A, const bfraw* __restrict__ Wsw,
    const float* __restrict__ bias, bfraw* __restrict__ Cb)
{
  __shared__ bfraw Wl[16384];
  const int tid = threadIdx.x;
  const long blockRow = (long)blockIdx.x * 128;
  #pragma unroll
  for (int i=0;i<8;i++)
    *reinterpret_cast<uint4*>(Wl + (i*256+tid)*8) =
        *reinterpret_cast<const uint4*>(Wsw + (i*256+tid)*8);
  __syncthreads();
  bf16x8 a0[4], a1[4];
  load_afrags_bf16(A, blockRow, tid, a0, a1);
  f32x4 acc0[8], acc1[8];
  mfma_128(Wl, tid & 63, a0, a1, acc0, acc1);
  gemm_store_bf16(acc0, acc1, bias, Cb, blockRow, tid);
}

// ---- 3 GEMMs sharing one A-read (+ optional 24-col score GEMM tail) ----------------
// Each block: load a-frags once; loop over 3 weights staged serially in LDS.
__global__ __launch_bounds__(256) void gemm3_k(
    const bfraw* __restrict__ A,
    const bfraw* __restrict__ W0, const bfraw* __restrict__ W1,
    const bfraw* __restrict__ W2,
    const float* __restrict__ b0, const float* __restrict__ b1,
    const float* __restrict__ b2,
    bfraw* __restrict__ O0, bfraw* __restrict__ O1, bfraw* __restrict__ O2,
    const bfraw* __restrict__ Psw, float* __restrict__ SS)
{
  __shared__ bfraw Wl[16384];
  const int tid = threadIdx.x;
  const long blockRow = (long)blockIdx.x * 128;
  const int w = tid >> 6, lane = tid & 63;
  bf16x8 a0[4], a1[4];
  load_afrags_bf16(A, blockRow, tid, a0, a1);
  const bfraw* Ws[3] = {W0, W1, W2};
  const float* bs[3] = {b0, b1, b2};
  bfraw* Os[3] = {O0, O1, O2};
  #pragma unroll
  for (int t=0;t<3;t++){
    __syncthreads();                                 // prev readers done
    #pragma unroll
    for (int i=0;i<8;i++)
      *reinterpret_cast<uint4*>(Wl + (i*256+tid)*8) =
          *reinterpret_cast<const uint4*>(Ws[t] + (i*256+tid)*8);
    __syncthreads();
    f32x4 acc0[8], acc1[8];
    mfma_128(Wl, lane, a0, a1, acc0, acc1);
    gemm_store_bf16(acc0, acc1, bs[t], Os[t], blockRow, tid);
  }
  if (Psw){
    __syncthreads();
    #pragma unroll
    for (int i=0;i<2;i++)
      *reinterpret_cast<uint4*>(Wl + (i*256+tid)*8) =
          *reinterpret_cast<const uint4*>(Psw + (i*256+tid)*8);
    __syncthreads();
    const f32x4 zz = {0.f,0.f,0.f,0.f};
    f32x4 acc0[2], acc1[2];
    #pragma unroll
    for (int nt=0;nt<2;nt++){ acc0[nt]=zz; acc1[nt]=zz; }
    #pragma unroll
    for (int nt=0;nt<2;nt++){
      #pragma unroll
      for (int kc=0;kc<4;kc++){
        bf16x8 b = *reinterpret_cast<const bf16x8*>(Wl + ((nt*4+kc)*64 + lane)*8);
        acc0[nt] = __builtin_amdgcn_mfma_f32_16x16x32_bf16(a0[kc], b, acc0[nt], 0, 0, 0);
        acc1[nt] = __builtin_amdgcn_mfma_f32_16x16x32_bf16(a1[kc], b, acc1[nt], 0, 0, 0);
      }
    }
    const int q = lane >> 4;
    #pragma unroll
    for (int g=0; g<2; g++){
      #pragma unroll
      for (int nt=0;nt<2;nt++){
        int col = nt*16 + (lane & 15);
        if (col < 24){
          int tt = col >> 3, c = col & 7;           // SS layout [T][NN][8]
          #pragma unroll
          for (int r=0;r<4;r++){
            long row = blockRow + w*32 + g*16 + q*4 + r;
            SS[(((long)tt*NN + row)<<3) + c] = (g ? acc1[nt][r] : acc0[nt][r]);
          }
        }
      }
    }
  }
}

// GEMM + res3 epilogue: v = g*out + (1-g)*x2; x3 = lrelu(x2 + norm*rms(v)); X in-place
__global__ __launch_bounds__(256) void gemm_res3_k(
    const bfraw* __restrict__ A, const bfraw* __restrict__ Wsw,
    const float* __restrict__ bias, float* __restrict__ X,
    const float* __restrict__ norm, const float* __restrict__ skip)
{
  __shared__ bfraw Wl[16384];
  const int tid = threadIdx.x;
  const long blockRow = (long)blockIdx.x * 128;
  #pragma unroll
  for (int i=0;i<8;i++)
    *reinterpret_cast<uint4*>(Wl + (i*256+tid)*8) =
        *reinterpret_cast<const uint4*>(Wsw + (i*256+tid)*8);
  __syncthreads();
  bf16x8 a0[4], a1[4];
  load_afrags_bf16(A, blockRow, tid, a0, a1);
  f32x4 acc0[8], acc1[8];
  mfma_128(Wl, tid & 63, a0, a1, acc0, acc1);
  const int w = tid>>6, lane = tid&63, q = lane>>4;
  const float gsk = 1.f/(1.f + __expf(-skip[0]));
  #pragma unroll
  for (int g=0; g<2; g++){
    #pragma unroll
    for (int r=0;r<4;r++){
      long row = blockRow + w*32 + g*16 + q*4 + r;
      float vv[8], xx[8];
      float sq = 0.f;
      #pragma unroll
      for (int nt=0;nt<8;nt++){
        int col = nt*16 + (lane & 15);
        float o  = (g ? acc1[nt][r] : acc0[nt][r]) + bias[col];
        float xo = X[row*DDIM + col];
        float v  = gsk*o + (1.f-gsk)*xo;
        vv[nt] = v; xx[nt] = xo; sq += v*v;
      }
      sq += __shfl_xor(sq, 1, 64);
      sq += __shfl_xor(sq, 2, 64);
      sq += __shfl_xor(sq, 4, 64);
      sq += __shfl_xor(sq, 8, 64);
      float rr = rsqrtf(sq*(1.f/DDIM) + EPSV);
      #pragma unroll
      for (int nt=0;nt<8;nt++){
        int col = nt*16 + (lane & 15);
        X[row*DDIM + col] = lrelu(xx[nt] + norm[col]*vv[nt]*rr);
      }
    }
  }
}

// GEMM (A read directly from f32!) + FiLM epilogue:
// out = (1+gamma')*(acc+bias+x3) + beta'   (gbt pre-tanh'd)
__global__ __launch_bounds__(256) void gemm_film_k(
    const float* __restrict__ Af, const bfraw* __restrict__ Wsw,
    const float* __restrict__ bias, const float* __restrict__ Xadd,
    const float* __restrict__ gbt, float* __restrict__ out)
{
  __shared__ bfraw Wl[16384];
  const int tid = threadIdx.x;
  const long blockRow = (long)blockIdx.x * 128;
  #pragma unroll
  for (int i=0;i<8;i++)
    *reinterpret_cast<uint4*>(Wl + (i*256+tid)*8) =
        *reinterpret_cast<const uint4*>(Wsw + (i*256+tid)*8);
  __syncthreads();
  bf16x8 a0[4], a1[4];
  load_afrags_f32(Af, blockRow, tid, a0, a1);
  f32x4 acc0[8], acc1[8];
  mfma_128(Wl, tid & 63, a0, a1, acc0, acc1);
  const int w = tid>>6, lane = tid&63, q = lane>>4;
  #pragma unroll
  for (int g=0; g<2; g++){
    #pragma unroll
    for (int nt=0;nt<8;nt++){
      int col = nt*16 + (lane & 15);
      float bv = bias[col];
      #pragma unroll
      for (int r=0;r<4;r++){
        long row = blockRow + w*32 + g*16 + q*4 + r;
        long gi  = row >> 8;                              // 256 nodes per graph
        float v  = (g ? acc1[nt][r] : acc0[nt][r]) + bv + Xadd[row*DDIM + col];
        float ga = gbt[gi*256 + col];
        float be = gbt[gi*256 + 128 + col];
        out[row*DDIM + col] = (1.f + ga)*v + be;
      }
    }
  }
}

// ---------------- fused GAT: 3-type exp-softmax agg + bias + RMS + residual ---------
// SS layout: [T][NN][8], cols 0..3 = ss per head, 4..7 = ds per head.
__global__ __launch_bounds__(256) void gat_fused_k(
    const int* __restrict__ rp, const int* __restrict__ srcs,
    const bfraw* __restrict__ H0, const bfraw* __restrict__ H1,
    const bfraw* __restrict__ H2, const float* __restrict__ SS,
    const float* __restrict__ gatb, const float* __restrict__ xold,
    const float* __restrict__ norm, float* __restrict__ X, bfraw* __restrict__ Xb)
{
  int node = blockIdx.x*8 + (threadIdx.x >> 5);
  int l = threadIdx.x & 31;
  int hd = l >> 3;
  const bfraw* Hs[3] = {H0, H1, H2};
  float tx=0.f, ty=0.f, tz=0.f, tw=0.f;
  #pragma unroll
  for (int t=0; t<3; t++){
    const bfraw* Ht = Hs[t];
    const float* St = SS + ((long)t*NN)*8;
    float dsv = St[(long)node*8 + 4 + hd];
    float e = __expf(lrelu(St[(long)node*8 + hd] + dsv));   // self-loop
    float lsum = e;
    float4 a4 = ld_bf4(Ht + (long)node*DDIM + l*4);
    a4.x *= e; a4.y *= e; a4.z *= e; a4.w *= e;
    int beg = rp[t*(NN+1) + node], end = rp[t*(NN+1) + node + 1];
    const int* sp = srcs + (long)t*NEDGE;
    for (int p=beg; p<end; p++){
      int s = sp[p];
      float ee = __expf(lrelu(St[(long)s*8 + hd] + dsv));
      float4 hv = ld_bf4(Ht + (long)s*DDIM + l*4);
      lsum += ee;
      a4.x += ee*hv.x; a4.y += ee*hv.y; a4.z += ee*hv.z; a4.w += ee*hv.w;
    }
    float inv = 1.f/lsum;
    tx += a4.x*inv; ty += a4.y*inv; tz += a4.z*inv; tw += a4.w*inv;
  }
  int f = l*4;
  tx += gatb[f]   + gatb[DDIM+f]   + gatb[2*DDIM+f];
  ty += gatb[f+1] + gatb[DDIM+f+1] + gatb[2*DDIM+f+1];
  tz += gatb[f+2] + gatb[DDIM+f+2] + gatb[2*DDIM+f+2];
  tw += gatb[f+3] + gatb[DDIM+f+3] + gatb[2*DDIM+f+3];
  float sq = tx*tx + ty*ty + tz*tz + tw*tw;
  sq += __shfl_xor(sq, 1, 64);
  sq += __shfl_xor(sq, 2, 64);
  sq += __shfl_xor(sq, 4, 64);
  sq += __shfl_xor(sq, 8, 64);
  sq += __shfl_xor(sq, 16, 64);
  float r = rsqrtf(sq*(1.f/DDIM) + EPSV);
  float4 x4 = *reinterpret_cast<const float4*>(xold + (long)node*DDIM + f);
  float4 o;
  o.x = lrelu(x4.x + norm[f]  *tx*r);
  o.y = lrelu(x4.y + norm[f+1]*ty*r);
  o.z = lrelu(x4.z + norm[f+2]*tz*r);
  o.w = lrelu(x4.w + norm[f+3]*tw*r);
  *reinterpret_cast<float4*>(X + (long)node*DDIM + f) = o;
  unsigned int lo = ((unsigned int)f2bf(o.y) << 16) | f2bf(o.x);
  unsigned int hi = ((unsigned int)f2bf(o.w) << 16) | f2bf(o.z);
  *reinterpret_cast<uint2*>(Xb + (long)node*DDIM + f) = make_uint2(lo, hi);
}

// ---------------- HGT: fold rel into projection ----------------
__global__ void fold_k(const float* __restrict__ w, const float* __restrict__ b,
                       const float* __restrict__ rel, float* __restrict__ Weff,
                       float* __restrict__ beff)
{
  int idx = blockIdx.x*256 + threadIdx.x;
  if (idx >= NTYPE*DDIM*DDIM) return;
  int he = idx & 127, c = (idx >> 7) & 127, t = idx >> 14;
  int h = he >> 5, e = he & 31;
  const float* wrow = w + (long)c*DDIM + h*HDIM;
  const float* relm = rel + ((long)(t*NHEAD + h)*HDIM)*HDIM + e;
  float s = 0.f;
  #pragma unroll 8
  for (int d=0; d<HDIM; d++) s += wrow[d] * relm[d*HDIM];
  Weff[(long)t*DDIM*DDIM + (long)c*DDIM + he] = s;
  if (c == 0){
    float sb = 0.f;
    #pragma unroll 8
    for (int d=0; d<HDIM; d++) sb += b[h*HDIM+d] * relm[d*HDIM];
    beff[(long)t*DDIM + he] = sb;
  }
}

// ---------------- HGT phase A: per-edge exp(score) directly (no max) ----------------
__global__ __launch_bounds__(256) void hgt_score_pass_k(
    const int* __restrict__ rp, const int* __restrict__ srcs,
    const bfraw* __restrict__ qb, const bfraw* __restrict__ kt,
    const float* __restrict__ relp, float* __restrict__ E)
{
  int node = blockIdx.x*8 + (threadIdx.x >> 5);
  int l = threadIdx.x & 31;
  int hd = l >> 3, sub = l & 7;
  float4 qv = ld_bf4(qb + (long)node*DDIM + l*4);
  int beg = rp[node], end = rp[node+1];
  float scale = relp[hd] * 0.17677669529663687f;   // 1/sqrt(32)
  for (int p=beg; p<end; p++){
    int s = srcs[p];
    float4 kv = ld_bf4(kt + (long)s*DDIM + l*4);
    float dot = qv.x*kv.x + qv.y*kv.y + qv.z*kv.z + qv.w*kv.w;
    dot += __shfl_xor(dot, 1, 64);
    dot += __shfl_xor(dot, 2, 64);
    dot += __shfl_xor(dot, 4, 64);
    if (sub == 0) E[(long)p*4 + hd] = __expf(dot * scale);
  }
}

// ---------------- HGT fused acc: 3 types, registers only, gelu finalize -> bf16 -----
__global__ __launch_bounds__(256) void hgt_acc_fused_k(
    const int* __restrict__ rp, const int* __restrict__ srcs,
    const float* __restrict__ E, const bfraw* __restrict__ V0,
    const bfraw* __restrict__ V1, const bfraw* __restrict__ V2,
    bfraw* __restrict__ out)
{
  int node = blockIdx.x*8 + (threadIdx.x >> 5);
  int l = threadIdx.x & 31;
  int hd = l >> 3;
  float ax=0.f, ay=0.f, az=0.f, aw=0.f, lsum=0.f;
  const bfraw* Vs[3] = {V0, V1, V2};
  #pragma unroll
  for (int t=0; t<3; t++){
    const bfraw* Vt = Vs[t];
    const float* Ep = E + (long)t*NEDGE*4;
    const int* sp = srcs + (long)t*NEDGE;
    int beg = rp[t*(NN+1) + node], end = rp[t*(NN+1) + node + 1];
    for (int p=beg; p<end; p++){
      int s = sp[p];
      float ex = Ep[(long)p*4 + hd];
      float4 vv = ld_bf4(Vt + (long)s*DDIM + l*4);
      ax += ex*vv.x; ay += ex*vv.y; az += ex*vv.z; aw += ex*vv.w;
      lsum += ex;
    }
  }
  float inv = (lsum > 0.f) ? 1.f/lsum : 0.f;
  float o0 = gelu_f(ax*inv), o1 = gelu_f(ay*inv);
  float o2 = gelu_f(az*inv), o3 = gelu_f(aw*inv);
  unsigned int lo = ((unsigned int)f2bf(o1) << 16) | f2bf(o0);
  unsigned int hi = ((unsigned int)f2bf(o3) << 16) | f2bf(o2);
  *reinterpret_cast<uint2*>(out + (long)node*DDIM + l*4) = make_uint2(lo, hi);
}

// ---------------- FiLM ----------------
__global__ void film1_k(const float* __restrict__ z, const float* __restrict__ w1,
                        const float* __restrict__ b1, float* __restrict__ f1)
{
  int idx = blockIdx.x*256 + threadIdx.x;
  if (idx >= NGRAPH*256) return;
  int j = idx & 255, b = idx >> 8;
  const float* zr = z + (long)b*DDIM;
  float s = b1[j];
  for (int k=0;k<DDIM;k++) s += zr[k] * w1[(long)k*256 + j];
  f1[idx] = gelu_f(s);
}

__global__ void film2_k(const float* __restrict__ f1, const float* __restrict__ w2,
                        const float* __restrict__ b2, float* __restrict__ gb)
{
  int idx = blockIdx.x*256 + threadIdx.x;
  if (idx >= NGRAPH*256) return;
  int j = idx & 255, b = idx >> 8;
  const float* fr = f1 + (long)b*256;
  float s = b2[j];
  for (int k=0;k<256;k++) s += fr[k] * w2[(long)k*256 + j];
  gb[idx] = 0.1f*tanhf(s);                       // pre-apply 0.1*tanh for epilogue
}

// ---------------- host ----------------
extern "C" void kernel_launch(void* const* d_in, const int* in_sizes, int n_in,
                              void* d_out, int out_size, void* d_ws, size_t ws_size,
                              hipStream_t stream)
{
  (void)in_sizes; (void)n_in; (void)out_size; (void)ws_size;
  const float* x_cell = (const float*)d_in[0];
  const float* x_emb  = (const float*)d_in[1];
  const float* z_h    = (const float*)d_in[2];
  const int*   ei     = (const int*)d_in[3];
  const float* gw[2]  = {(const float*)d_in[4],  (const float*)d_in[8]};
  const float* gas[2] = {(const float*)d_in[5],  (const float*)d_in[9]};
  const float* gad[2] = {(const float*)d_in[6],  (const float*)d_in[10]};
  const float* gbi[2] = {(const float*)d_in[7],  (const float*)d_in[11]};
  const float* norm1  = (const float*)d_in[12];
  const float* norm2  = (const float*)d_in[13];
  const float* norm3  = (const float*)d_in[14];
  const float* kw = (const float*)d_in[15]; const float* kb = (const float*)d_in[16];
  const float* qw = (const float*)d_in[17]; const float* qb = (const float*)d_in[18];
  const float* vw = (const float*)d_in[19]; const float* vb = (const float*)d_in[20];
  const float* relk = (const float*)d_in[21];
  const float* relv = (const float*)d_in[22];
  const float* relp = (const float*)d_in[23];
  const float* aw = (const float*)d_in[24]; const float* ab = (const float*)d_in[25];
  const float* skip = (const float*)d_in[26];
  const float* injw = (const float*)d_in[27]; const float* injb = (const float*)d_in[28];
  const float* fw1 = (const float*)d_in[29]; const float* fb1 = (const float*)d_in[30];
  const float* fw2 = (const float*)d_in[31]; const float* fb2 = (const float*)d_in[32];

  const long ND = (long)NN*DDIM;
  float* X    = (float*)d_ws;                    // x1 / x2 / x3 (f32)
  float* K    = X + ND;                          // 2x bf16 buffers (H1/H2, q/kt1, V1/V2)
  bfraw* Xb   = (bfraw*)(K + ND);                // bf16 GEMM A; later HGT attn out
  bfraw* Hb   = Xb + ND;                         // bf16: h0 / kt0/kt2 / vt0
  float* Sbuf = (float*)(Hb + ND);               // GAT SS [T][N][8] | HGT E [3E][4]
  float* sA   = Sbuf + (long)NTYPE*NEDGE*4;      // spare
  float* sB   = sA + (long)NN*4;                 // spare
  float* WkE  = sB + (long)NN*4;
  float* bkE  = WkE + (long)NTYPE*DDIM*DDIM;
  float* WvE  = bkE + (long)NTYPE*DDIM;
  float* bvE  = WvE + (long)NTYPE*DDIM*DDIM;
  bfraw* Pswz = (bfraw*)(bvE + (long)NTYPE*DDIM);   // 2 layers x 4096 bf16
  bfraw* Wall = Pswz + (long)2*4096;                // 15 swizzled bf16 weights
  float* f1b  = (float*)(Wall + (long)15*16384);
  float* gbb  = f1b + (long)NGRAPH*256;
  int*   deg  = (int*)(gbb + (long)NGRAPH*256);  // 3N (reused as cnt)
  int*   rp   = deg + (long)NTYPE*NN;            // 3(N+1)
  int*   srcs = rp  + (long)NTYPE*(NN+1);        // 3E
  int*   csum = srcs + (long)NTYPE*NEDGE;        // 192

  bfraw* Kb0 = (bfraw*)K;                        // K as 2 bf16 buffers
  bfraw* Kb1 = Kb0 + ND;

  const dim3 b256(256);
  float* NF = nullptr;
  bfraw* NB = nullptr; (void)NB;

  // ---------- CSR build ----------
  fill_k<<<256, b256, 0, stream>>>((float*)deg, 0.f, NTYPE*NN);
  hist_k<<<(NTYPE*NEDGE)/256, b256, 0, stream>>>(ei, deg);
  scan_a_k<<<dim3(64, NTYPE), b256, 0, stream>>>(deg, rp, csum);
  scan_b_k<<<NTYPE, 64, 0, stream>>>(csum);
  scan_c_k<<<dim3(64, NTYPE), b256, 0, stream>>>(rp, csum);
  fill_k<<<256, b256, 0, stream>>>((float*)deg, 0.f, NTYPE*NN);   // cnt
  scatter_k<<<(NTYPE*NEDGE)/256, b256, 0, stream>>>(ei, rp, deg, srcs);

  // ---------- weight prep ----------
  fold_k<<<(NTYPE*DDIM*DDIM)/256, b256, 0, stream>>>(kw, kb, relk, WkE, bkE);
  fold_k<<<(NTYPE*DDIM*DDIM)/256, b256, 0, stream>>>(vw, vb, relv, WvE, bvE);
  wswz_k<<<dim3(64, 15), b256, 0, stream>>>(
      gw[0], gw[0]+16384, gw[0]+32768,
      gw[1], gw[1]+16384, gw[1]+32768,
      qw, WkE, WvE, aw, injw, Wall);
  gatproj_k<<<16, b256, 0, stream>>>(gw[0], gas[0], gad[0], Pswz);
  gatproj_k<<<16, b256, 0, stream>>>(gw[1], gas[1], gad[1], Pswz + 4096);

  // ---------- FiLM (independent, run early) ----------
  film1_k<<<(NGRAPH*256)/256, b256, 0, stream>>>(z_h, fw1, fb1, f1b);
  film2_k<<<(NGRAPH*256)/256, b256, 0, stream>>>(f1b, fw2, fb2, gbb);

  // ---------- GAT layers ----------
  conv_k<<<2048, b256, 0, stream>>>(x_cell, Xb, (int)ND);
  for (int layer=0; layer<2; layer++){
    gemm3_k<<<NN/128, b256, 0, stream>>>(
        Xb,
        Wall + (long)(layer*3+0)*16384, Wall + (long)(layer*3+1)*16384,
        Wall + (long)(layer*3+2)*16384,
        NF, NF, NF,
        Hb, Kb0, Kb1,
        Pswz + (long)layer*4096, Sbuf);
    gat_fused_k<<<NN/8, b256, 0, stream>>>(
        rp, srcs, Hb, Kb0, Kb1, Sbuf, gbi[layer],
        (layer==0) ? x_cell : X, (layer==0) ? norm1 : norm2, X, Xb);
  }

  // ---------- HGT ----------
  // q (bf16) -> Kb0, kt0 -> Hb, kt1 -> Kb1, all reading A once
  gemm3_k<<<NN/128, b256, 0, stream>>>(
      Xb, Wall + (long)6*16384, Wall + (long)7*16384, Wall + (long)8*16384,
      qb, bkE, bkE + DDIM,
      Kb0, Hb, Kb1, nullptr, nullptr);
  hgt_score_pass_k<<<NN/8, b256, 0, stream>>>(rp, srcs, Kb0, Hb, relp, Sbuf);
  hgt_score_pass_k<<<NN/8, b256, 0, stream>>>(rp + (NN+1), srcs + NEDGE, Kb0, Kb1,
      relp + NHEAD, Sbuf + (long)NEDGE*4);
  gemm_out_k<<<NN/128, b256, 0, stream>>>(Xb, Wall + (long)9*16384, bkE + 2*DDIM, Hb);
  hgt_score_pass_k<<<NN/8, b256, 0, stream>>>(rp + 2*(NN+1), srcs + 2*NEDGE, Kb0, Hb,
      relp + 2*NHEAD, Sbuf + (long)2*NEDGE*4);
  // vt0..2 -> Hb, Kb0 (q dead), Kb1 (kt1 dead), reading A once
  gemm3_k<<<NN/128, b256, 0, stream>>>(
      Xb, Wall + (long)10*16384, Wall + (long)11*16384, Wall + (long)12*16384,
      bvE, bvE + DDIM, bvE + 2*DDIM,
      Hb, Kb0, Kb1, nullptr, nullptr);
  hgt_acc_fused_k<<<NN/8, b256, 0, stream>>>(rp, srcs, Sbuf, Hb, Kb0, Kb1, Xb);
  gemm_res3_k<<<NN/128, b256, 0, stream>>>(Xb, Wall + (long)13*16384, ab,
                                           X, norm3, skip);                  // x3 in X
  gemm_film_k<<<NN/128, b256, 0, stream>>>(x_emb, Wall + (long)14*16384, injb,
                                           X, gbb, (float*)d_out);
}

// Round 3
// 878.122 us; speedup vs baseline: 1.5347x; 1.0962x over previous
//
#include <hip/hip_runtime.h>
#include <math.h>
#include <cstdint>

// ---------------- problem constants ----------------
#define NN     131072     // nodes
#define DDIM   128        // hidden dim
#define NHEAD  4
#define HDIM   32
#define NTYPE  3
#define NEDGE  262144     // edges per type (2^18)
#define NGRAPH 512
#define EPSV   1e-6f
#define SLOPEV 0.2f

typedef unsigned short bfraw;
typedef __attribute__((ext_vector_type(8))) short bf16x8;
typedef __attribute__((ext_vector_type(4))) float f32x4;

// ---------------- helpers ----------------
__device__ __forceinline__ float lrelu(float x){ return x >= 0.f ? x : SLOPEV*x; }
__device__ __forceinline__ float gelu_f(float x){ return 0.5f*x*(1.f+erff(x*0.70710678118654752f)); }
__device__ __forceinline__ bfraw f2bf(float f){
  unsigned int u = __float_as_uint(f);
  u += 0x7fffu + ((u >> 16) & 1u);          // RNE
  return (bfraw)(u >> 16);
}
__device__ __forceinline__ float4 ld_bf4(const bfraw* p){
  uint2 u = *reinterpret_cast<const uint2*>(p);
  float4 r;
  r.x = __uint_as_float(u.x << 16); r.y = __uint_as_float(u.x & 0xffff0000u);
  r.z = __uint_as_float(u.y << 16); r.w = __uint_as_float(u.y & 0xffff0000u);
  return r;
}
__device__ __forceinline__ bf16x8 pack_bf8(const float* p){
  float4 u = *reinterpret_cast<const float4*>(p);
  float4 v = *reinterpret_cast<const float4*>(p+4);
  bf16x8 r;
  r[0]=(short)f2bf(u.x); r[1]=(short)f2bf(u.y); r[2]=(short)f2bf(u.z); r[3]=(short)f2bf(u.w);
  r[4]=(short)f2bf(v.x); r[5]=(short)f2bf(v.y); r[6]=(short)f2bf(v.z); r[7]=(short)f2bf(v.w);
  return r;
}

// ---------------- generic fill ----------------
__global__ void fill_k(float* __restrict__ p, float v, int n){
  int i = blockIdx.x*blockDim.x + threadIdx.x;
  int stride = gridDim.x*blockDim.x;
  for (; i < n; i += stride) p[i] = v;
}

// ---------------- CSR build (dst-sorted, per edge type) ----------------
__global__ void hist_k(const int* __restrict__ ei, int* __restrict__ deg){
  int idx = blockIdx.x*256 + threadIdx.x;          // < 3E
  int t = idx >> 18, e = idx & (NEDGE-1);
  int d = ei[(long)t*2*NEDGE + NEDGE + e];
  atomicAdd(&deg[t*NN + d], 1);
}

__global__ void scan_a_k(const int* __restrict__ deg, int* __restrict__ rp,
                         int* __restrict__ csum){
  __shared__ int sh[256];
  int t = blockIdx.y, chunk = blockIdx.x, tid = threadIdx.x;
  const int* dp = deg + (long)t*NN + chunk*2048 + tid*8;
  int v[8]; int s = 0;
  #pragma unroll
  for (int i=0;i<8;i++){ v[i] = dp[i]; s += v[i]; }
  sh[tid] = s; __syncthreads();
  for (int off=1; off<256; off<<=1){
    int x = (tid>=off) ? sh[tid-off] : 0;
    __syncthreads();
    sh[tid] += x;
    __syncthreads();
  }
  int run = sh[tid] - s;                            // exclusive prefix
  int* op = rp + (long)t*(NN+1) + chunk*2048 + tid*8;
  #pragma unroll
  for (int i=0;i<8;i++){ op[i] = run; run += v[i]; }
  if (tid == 255) csum[t*64 + chunk] = sh[255];
}

__global__ void scan_b_k(int* __restrict__ csum){
  __shared__ int sh[64];
  int t = blockIdx.x, tid = threadIdx.x;
  int s = csum[t*64 + tid];
  sh[tid] = s; __syncthreads();
  for (int off=1; off<64; off<<=1){
    int x = (tid>=off) ? sh[tid-off] : 0;
    __syncthreads();
    sh[tid] += x;
    __syncthreads();
  }
  csum[t*64 + tid] = sh[tid] - s;                   // exclusive
}

__global__ void scan_c_k(int* __restrict__ rp, const int* __restrict__ csum){
  int t = blockIdx.y, chunk = blockIdx.x, tid = threadIdx.x;
  int add = csum[t*64 + chunk];
  int* op = rp + (long)t*(NN+1) + chunk*2048 + tid*8;
  #pragma unroll
  for (int i=0;i<8;i++) op[i] += add;
  if (chunk == 63 && tid == 255) rp[(long)t*(NN+1) + NN] = NEDGE;
}

__global__ void scatter_k(const int* __restrict__ ei, const int* __restrict__ rp,
                          int* __restrict__ cnt, int* __restrict__ srcs){
  int idx = blockIdx.x*256 + threadIdx.x;          // < 3E
  int t = idx >> 18, e = idx & (NEDGE-1);
  int s = ei[(long)t*2*NEDGE + e];
  int d = ei[(long)t*2*NEDGE + NEDGE + e];
  int pos = rp[(long)t*(NN+1) + d] + atomicAdd(&cnt[t*NN + d], 1);
  srcs[(long)t*NEDGE + pos] = s;
}

// ---------------- weight swizzle: f32 [128,128] -> bf16 b-frag layout ----------------
// Wsw[((nt*4+kc)*64+lane)*8+j] = W[kc*32+(lane>>4)*8+j][nt*16+(lane&15)]
__global__ void wswz_k(const float* g0a, const float* g0b, const float* g0c,
                       const float* g1a, const float* g1b, const float* g1c,
                       const float* qw,
                       const float* wk, const float* wv,   // [3][128][128] each
                       const float* aw, const float* injw,
                       bfraw* __restrict__ Wall)
{
  int y = blockIdx.y;
  const float* src;
  switch(y){
    case 0: src = g0a; break;  case 1: src = g0b; break;  case 2: src = g0c; break;
    case 3: src = g1a; break;  case 4: src = g1b; break;  case 5: src = g1c; break;
    case 6: src = qw; break;
    case 7: case 8: case 9: src = wk + (long)(y-7)*16384; break;
    case 10: case 11: case 12: src = wv + (long)(y-10)*16384; break;
    case 13: src = aw; break;
    default: src = injw; break;
  }
  int i = blockIdx.x*256 + threadIdx.x;            // < 16384
  int j = i & 7, lane = (i>>3) & 63, kc = (i>>9) & 3, nt = i >> 11;
  int k = kc*32 + ((lane>>4)<<3) + j;
  int n = nt*16 + (lane & 15);
  Wall[(long)y*16384 + i] = f2bf(src[k*DDIM + n]);
}

// ---------------- GAT score projection, directly in swizzled b-frag layout ----------
__global__ void gatproj_k(const float* __restrict__ w, const float* __restrict__ asrc,
                          const float* __restrict__ adst, bfraw* __restrict__ out)
{
  int i = blockIdx.x*256 + threadIdx.x;            // < 4096
  int j = i & 7, lane = (i>>3) & 63, kc = (i>>9) & 3, nt = i >> 11;   // nt 0..1
  int k = kc*32 + ((lane>>4)<<3) + j;
  int n = nt*16 + (lane & 15);
  float s = 0.f;
  if (n < 24){
    int t = n >> 3, sd = (n >> 2) & 1, hh = n & 3;
    const float* a  = (sd ? adst : asrc) + ((long)t*NHEAD + hh)*HDIM;
    const float* wr = w + ((long)t*DDIM + k)*DDIM + hh*HDIM;
    #pragma unroll 8
    for (int dd=0; dd<HDIM; dd++) s += wr[dd]*a[dd];
  }
  out[i] = f2bf(s);
}

// ---------------- MFMA GEMM building blocks -----------------------------------------
__device__ __forceinline__ void load_afrags_bf16(const bfraw* __restrict__ A,
    long blockRow, int tid, bf16x8 a0[4], bf16x8 a1[4])
{
  const int w = tid >> 6, lane = tid & 63;
  const long rowA = blockRow + w*32 + (lane & 15);
  const bfraw* A0 = A + rowA*DDIM + ((lane>>4)<<3);
  #pragma unroll
  for (int kc=0;kc<4;kc++){
    a0[kc] = *reinterpret_cast<const bf16x8*>(A0 + kc*32);
    a1[kc] = *reinterpret_cast<const bf16x8*>(A0 + 16*DDIM + kc*32);
  }
}

__device__ __forceinline__ void load_afrags_f32(const float* __restrict__ A,
    long blockRow, int tid, bf16x8 a0[4], bf16x8 a1[4])
{
  const int w = tid >> 6, lane = tid & 63;
  const long rowA = blockRow + w*32 + (lane & 15);
  const float* A0 = A + rowA*DDIM + ((lane>>4)<<3);
  #pragma unroll
  for (int kc=0;kc<4;kc++){
    a0[kc] = pack_bf8(A0 + kc*32);
    a1[kc] = pack_bf8(A0 + 16*DDIM + kc*32);
  }
}

__device__ __forceinline__ void mfma_128(const bfraw* Wl, int lane,
    bf16x8 a0[4], bf16x8 a1[4], f32x4 acc0[8], f32x4 acc1[8])
{
  const f32x4 zz = {0.f,0.f,0.f,0.f};
  #pragma unroll
  for (int nt=0;nt<8;nt++){ acc0[nt]=zz; acc1[nt]=zz; }
  #pragma unroll
  for (int nt=0;nt<8;nt++){
    #pragma unroll
    for (int kc=0;kc<4;kc++){
      bf16x8 b = *reinterpret_cast<const bf16x8*>(Wl + ((nt*4+kc)*64 + lane)*8);
      acc0[nt] = __builtin_amdgcn_mfma_f32_16x16x32_bf16(a0[kc], b, acc0[nt], 0, 0, 0);
      acc1[nt] = __builtin_amdgcn_mfma_f32_16x16x32_bf16(a1[kc], b, acc1[nt], 0, 0, 0);
    }
  }
}

__device__ __forceinline__ void gemm_store_bf16(f32x4 acc0[8], f32x4 acc1[8],
    const float* bias, bfraw* __restrict__ Cb, long blockRow, int tid)
{
  const int w = tid>>6, lane = tid&63, q = lane>>4;
  #pragma unroll
  for (int g=0; g<2; g++){
    #pragma unroll
    for (int nt=0;nt<8;nt++){
      int col = nt*16 + (lane & 15);
      float bv = bias ? bias[col] : 0.f;
      #pragma unroll
      for (int r=0;r<4;r++){
        long row = blockRow + w*32 + g*16 + q*4 + r;
        float v = (g ? acc1[nt][r] : acc0[nt][r]) + bv;
        Cb[row*DDIM + col] = f2bf(v);
      }
    }
  }
}

// generic single GEMM: bf16 out, optional bias
__global__ __launch_bounds__(256) void gemm_out_k(
    const bfraw* __restrict__ A, const bfraw* __restrict__ Wsw,
    const float* __restrict__ bias, bfraw* __restrict__ Cb)
{
  __shared__ bfraw Wl[16384];
  const int tid = threadIdx.x;
  const long blockRow = (long)blockIdx.x * 128;
  #pragma unroll
  for (int i=0;i<8;i++)
    *reinterpret_cast<uint4*>(Wl + (i*256+tid)*8) =
        *reinterpret_cast<const uint4*>(Wsw + (i*256+tid)*8);
  __syncthreads();
  bf16x8 a0[4], a1[4];
  load_afrags_bf16(A, blockRow, tid, a0, a1);
  f32x4 acc0[8], acc1[8];
  mfma_128(Wl, tid & 63, a0, a1, acc0, acc1);
  gemm_store_bf16(acc0, acc1, bias, Cb, blockRow, tid);
}

// ---- 3 GEMMs sharing one A-read (+ optional 24-col score GEMM tail) ----------------
// A source: bf16 (Ab) or f32 (Af, converted in-register) — Af wins if non-null.
__global__ __launch_bounds__(256) void gemm3_k(
    const bfraw* __restrict__ Ab, const float* __restrict__ Af,
    const bfraw* __restrict__ W0, const bfraw* __restrict__ W1,
    const bfraw* __restrict__ W2,
    const float* __restrict__ b0, const float* __restrict__ b1,
    const float* __restrict__ b2,
    bfraw* __restrict__ O0, bfraw* __restrict__ O1, bfraw* __restrict__ O2,
    const bfraw* __restrict__ Psw, float* __restrict__ SS)
{
  __shared__ bfraw Wl[16384];
  const int tid = threadIdx.x;
  const long blockRow = (long)blockIdx.x * 128;
  const int w = tid >> 6, lane = tid & 63;
  bf16x8 a0[4], a1[4];
  if (Af) load_afrags_f32(Af, blockRow, tid, a0, a1);
  else    load_afrags_bf16(Ab, blockRow, tid, a0, a1);
  const bfraw* Ws[3] = {W0, W1, W2};
  const float* bs[3] = {b0, b1, b2};
  bfraw* Os[3] = {O0, O1, O2};
  #pragma unroll
  for (int t=0;t<3;t++){
    __syncthreads();                                 // prev readers done
    #pragma unroll
    for (int i=0;i<8;i++)
      *reinterpret_cast<uint4*>(Wl + (i*256+tid)*8) =
          *reinterpret_cast<const uint4*>(Ws[t] + (i*256+tid)*8);
    __syncthreads();
    f32x4 acc0[8], acc1[8];
    mfma_128(Wl, lane, a0, a1, acc0, acc1);
    gemm_store_bf16(acc0, acc1, bs[t], Os[t], blockRow, tid);
  }
  if (Psw){
    __syncthreads();
    #pragma unroll
    for (int i=0;i<2;i++)
      *reinterpret_cast<uint4*>(Wl + (i*256+tid)*8) =
          *reinterpret_cast<const uint4*>(Psw + (i*256+tid)*8);
    __syncthreads();
    const f32x4 zz = {0.f,0.f,0.f,0.f};
    f32x4 acc0[2], acc1[2];
    #pragma unroll
    for (int nt=0;nt<2;nt++){ acc0[nt]=zz; acc1[nt]=zz; }
    #pragma unroll
    for (int nt=0;nt<2;nt++){
      #pragma unroll
      for (int kc=0;kc<4;kc++){
        bf16x8 b = *reinterpret_cast<const bf16x8*>(Wl + ((nt*4+kc)*64 + lane)*8);
        acc0[nt] = __builtin_amdgcn_mfma_f32_16x16x32_bf16(a0[kc], b, acc0[nt], 0, 0, 0);
        acc1[nt] = __builtin_amdgcn_mfma_f32_16x16x32_bf16(a1[kc], b, acc1[nt], 0, 0, 0);
      }
    }
    const int q = lane >> 4;
    #pragma unroll
    for (int g=0; g<2; g++){
      #pragma unroll
      for (int nt=0;nt<2;nt++){
        int col = nt*16 + (lane & 15);
        if (col < 24){
          int tt = col >> 3, c = col & 7;           // SS layout [T][NN][8]
          #pragma unroll
          for (int r=0;r<4;r++){
            long row = blockRow + w*32 + g*16 + q*4 + r;
            SS[(((long)tt*NN + row)<<3) + c] = (g ? acc1[nt][r] : acc0[nt][r]);
          }
        }
      }
    }
  }
}

// ---- fused: GEMM(attn@aw) + res3 + GEMM(x_emb@injw) + FiLM -> out ------------------
// x3 never materialized. gbt pre-tanh'd.
__global__ __launch_bounds__(256) void gemm_r3film_k(
    const bfraw* __restrict__ Aattn, const bfraw* __restrict__ Waw,
    const float* __restrict__ ab, const float* __restrict__ X,
    const float* __restrict__ norm, const float* __restrict__ skip,
    const float* __restrict__ xemb, const bfraw* __restrict__ Winj,
    const float* __restrict__ injb, const float* __restrict__ gbt,
    float* __restrict__ out)
{
  __shared__ bfraw Wl[16384];
  const int tid = threadIdx.x;
  const long blockRow = (long)blockIdx.x * 128;
  // GEMM1: attn-out @ aw
  #pragma unroll
  for (int i=0;i<8;i++)
    *reinterpret_cast<uint4*>(Wl + (i*256+tid)*8) =
        *reinterpret_cast<const uint4*>(Waw + (i*256+tid)*8);
  __syncthreads();
  bf16x8 a0[4], a1[4];
  load_afrags_bf16(Aattn, blockRow, tid, a0, a1);
  f32x4 accA0[8], accA1[8];
  mfma_128(Wl, tid & 63, a0, a1, accA0, accA1);
  __syncthreads();
  // GEMM2: x_emb(f32) @ injw
  #pragma unroll
  for (int i=0;i<8;i++)
    *reinterpret_cast<uint4*>(Wl + (i*256+tid)*8) =
        *reinterpret_cast<const uint4*>(Winj + (i*256+tid)*8);
  __syncthreads();
  load_afrags_f32(xemb, blockRow, tid, a0, a1);
  f32x4 accB0[8], accB1[8];
  mfma_128(Wl, tid & 63, a0, a1, accB0, accB1);
  // epilogue
  const int w = tid>>6, lane = tid&63, q = lane>>4;
  const float gsk = 1.f/(1.f + __expf(-skip[0]));
  #pragma unroll
  for (int g=0; g<2; g++){
    #pragma unroll
    for (int r=0;r<4;r++){
      long row = blockRow + w*32 + g*16 + q*4 + r;
      float vv[8], xx[8];
      float sq = 0.f;
      #pragma unroll
      for (int nt=0;nt<8;nt++){
        int col = nt*16 + (lane & 15);
        float oA = (g ? accA1[nt][r] : accA0[nt][r]) + ab[col];
        float xo = X[row*DDIM + col];
        float v  = gsk*oA + (1.f-gsk)*xo;
        vv[nt] = v; xx[nt] = xo; sq += v*v;
      }
      sq += __shfl_xor(sq, 1, 64);
      sq += __shfl_xor(sq, 2, 64);
      sq += __shfl_xor(sq, 4, 64);
      sq += __shfl_xor(sq, 8, 64);
      float rr = rsqrtf(sq*(1.f/DDIM) + EPSV);
      long gi = row >> 8;                             // 256 nodes per graph
      #pragma unroll
      for (int nt=0;nt<8;nt++){
        int col = nt*16 + (lane & 15);
        float x3 = lrelu(xx[nt] + norm[col]*vv[nt]*rr);
        float vB = (g ? accB1[nt][r] : accB0[nt][r]) + injb[col] + x3;
        out[row*DDIM + col] = (1.f + gbt[gi*256 + col])*vB + gbt[gi*256 + 128 + col];
      }
    }
  }
}

// ---------------- fused GAT: 3-type exp-softmax agg + bias + RMS + residual ---------
// SS layout: [T][NN][8], cols 0..3 = ss per head, 4..7 = ds per head.
__global__ __launch_bounds__(256) void gat_fused_k(
    const int* __restrict__ rp, const int* __restrict__ srcs,
    const bfraw* __restrict__ H0, const bfraw* __restrict__ H1,
    const bfraw* __restrict__ H2, const float* __restrict__ SS,
    const float* __restrict__ gatb, const float* __restrict__ xold,
    const float* __restrict__ norm, float* __restrict__ X, bfraw* __restrict__ Xb)
{
  int node = blockIdx.x*8 + (threadIdx.x >> 5);
  int l = threadIdx.x & 31;
  int hd = l >> 3;
  const bfraw* Hs[3] = {H0, H1, H2};
  // hoist all per-type self data + ranges (independent loads issue together)
  float dsv[3], ssl[3]; float4 hsl[3]; int beg[3], end[3];
  #pragma unroll
  for (int t=0; t<3; t++){
    const float* St = SS + ((long)t*NN)*8;
    dsv[t] = St[(long)node*8 + 4 + hd];
    ssl[t] = St[(long)node*8 + hd];
    hsl[t] = ld_bf4(Hs[t] + (long)node*DDIM + l*4);
    beg[t] = rp[t*(NN+1) + node];
    end[t] = rp[t*(NN+1) + node + 1];
  }
  float tx=0.f, ty=0.f, tz=0.f, tw=0.f;
  #pragma unroll
  for (int t=0; t<3; t++){
    const bfraw* Ht = Hs[t];
    const float* St = SS + ((long)t*NN)*8;
    const int* sp = srcs + (long)t*NEDGE;
    const float d = dsv[t];
    float e = __expf(lrelu(ssl[t] + d));             // self-loop
    float lA = e, lB = 0.f;
    float4 aA = make_float4(e*hsl[t].x, e*hsl[t].y, e*hsl[t].z, e*hsl[t].w);
    float4 aB = make_float4(0.f,0.f,0.f,0.f);
    int p = beg[t];
    for (; p+1 < end[t]; p += 2){                    // 2-wide: dual chains
      int s0 = sp[p], s1 = sp[p+1];
      float v0 = St[(long)s0*8 + hd];
      float v1 = St[(long)s1*8 + hd];
      float4 h0 = ld_bf4(Ht + (long)s0*DDIM + l*4);
      float4 h1 = ld_bf4(Ht + (long)s1*DDIM + l*4);
      float e0 = __expf(lrelu(v0 + d));
      float e1 = __expf(lrelu(v1 + d));
      lA += e0; lB += e1;
      aA.x += e0*h0.x; aA.y += e0*h0.y; aA.z += e0*h0.z; aA.w += e0*h0.w;
      aB.x += e1*h1.x; aB.y += e1*h1.y; aB.z += e1*h1.z; aB.w += e1*h1.w;
    }
    if (p < end[t]){
      int s0 = sp[p];
      float e0 = __expf(lrelu(St[(long)s0*8 + hd] + d));
      float4 h0 = ld_bf4(Ht + (long)s0*DDIM + l*4);
      lA += e0;
      aA.x += e0*h0.x; aA.y += e0*h0.y; aA.z += e0*h0.z; aA.w += e0*h0.w;
    }
    float inv = 1.f/(lA + lB);
    tx += (aA.x+aB.x)*inv; ty += (aA.y+aB.y)*inv;
    tz += (aA.z+aB.z)*inv; tw += (aA.w+aB.w)*inv;
  }
  int f = l*4;
  tx += gatb[f]   + gatb[DDIM+f]   + gatb[2*DDIM+f];
  ty += gatb[f+1] + gatb[DDIM+f+1] + gatb[2*DDIM+f+1];
  tz += gatb[f+2] + gatb[DDIM+f+2] + gatb[2*DDIM+f+2];
  tw += gatb[f+3] + gatb[DDIM+f+3] + gatb[2*DDIM+f+3];
  float sq = tx*tx + ty*ty + tz*tz + tw*tw;
  sq += __shfl_xor(sq, 1, 64);
  sq += __shfl_xor(sq, 2, 64);
  sq += __shfl_xor(sq, 4, 64);
  sq += __shfl_xor(sq, 8, 64);
  sq += __shfl_xor(sq, 16, 64);
  float r = rsqrtf(sq*(1.f/DDIM) + EPSV);
  float4 x4 = *reinterpret_cast<const float4*>(xold + (long)node*DDIM + f);
  float4 o;
  o.x = lrelu(x4.x + norm[f]  *tx*r);
  o.y = lrelu(x4.y + norm[f+1]*ty*r);
  o.z = lrelu(x4.z + norm[f+2]*tz*r);
  o.w = lrelu(x4.w + norm[f+3]*tw*r);
  *reinterpret_cast<float4*>(X + (long)node*DDIM + f) = o;
  unsigned int lo = ((unsigned int)f2bf(o.y) << 16) | f2bf(o.x);
  unsigned int hi = ((unsigned int)f2bf(o.w) << 16) | f2bf(o.z);
  *reinterpret_cast<uint2*>(Xb + (long)node*DDIM + f) = make_uint2(lo, hi);
}

// ---------------- HGT: fold rel into projection (optional relp*1/sqrt(32) scale) ----
__global__ void fold_k(const float* __restrict__ w, const float* __restrict__ b,
                       const float* __restrict__ rel, const float* __restrict__ scl,
                       float* __restrict__ Weff, float* __restrict__ beff)
{
  int idx = blockIdx.x*256 + threadIdx.x;
  if (idx >= NTYPE*DDIM*DDIM) return;
  int he = idx & 127, c = (idx >> 7) & 127, t = idx >> 14;
  int h = he >> 5, e = he & 31;
  float fs = scl ? scl[t*NHEAD + h]*0.17677669529663687f : 1.f;   // 1/sqrt(32)
  const float* wrow = w + (long)c*DDIM + h*HDIM;
  const float* relm = rel + ((long)(t*NHEAD + h)*HDIM)*HDIM + e;
  float s = 0.f;
  #pragma unroll 8
  for (int d=0; d<HDIM; d++) s += wrow[d] * relm[d*HDIM];
  Weff[(long)t*DDIM*DDIM + (long)c*DDIM + he] = s*fs;
  if (c == 0){
    float sb = 0.f;
    #pragma unroll 8
    for (int d=0; d<HDIM; d++) sb += b[h*HDIM+d] * relm[d*HDIM];
    beff[(long)t*DDIM + he] = sb*fs;
  }
}

// ---------------- HGT scores: exp(q.kt) per edge (scale folded into kt) -------------
// 2-type version: q streamed once.
__global__ __launch_bounds__(256) void hgt_score2_k(
    const int* __restrict__ rp, const int* __restrict__ srcs,
    const bfraw* __restrict__ qb, const bfraw* __restrict__ kt0,
    const bfraw* __restrict__ kt1, float* __restrict__ E)
{
  int node = blockIdx.x*8 + (threadIdx.x >> 5);
  int l = threadIdx.x & 31;
  int hd = l >> 3, sub = l & 7;
  float4 qv = ld_bf4(qb + (long)node*DDIM + l*4);
  #pragma unroll
  for (int t=0; t<2; t++){
    const bfraw* kt = t ? kt1 : kt0;
    const int* sp = srcs + (long)t*NEDGE;
    float* Et = E + (long)t*NEDGE*4;
    int beg = rp[t*(NN+1) + node], end = rp[t*(NN+1) + node + 1];
    int p = beg;
    for (; p+1 < end; p += 2){
      int s0 = sp[p], s1 = sp[p+1];
      float4 k0 = ld_bf4(kt + (long)s0*DDIM + l*4);
      float4 k1 = ld_bf4(kt + (long)s1*DDIM + l*4);
      float d0 = qv.x*k0.x + qv.y*k0.y + qv.z*k0.z + qv.w*k0.w;
      float d1 = qv.x*k1.x + qv.y*k1.y + qv.z*k1.z + qv.w*k1.w;
      d0 += __shfl_xor(d0, 1, 64);  d1 += __shfl_xor(d1, 1, 64);
      d0 += __shfl_xor(d0, 2, 64);  d1 += __shfl_xor(d1, 2, 64);
      d0 += __shfl_xor(d0, 4, 64);  d1 += __shfl_xor(d1, 4, 64);
      if (sub == 0){
        Et[(long)p*4 + hd]     = __expf(d0);
        Et[(long)(p+1)*4 + hd] = __expf(d1);
      }
    }
    if (p < end){
      int s0 = sp[p];
      float4 k0 = ld_bf4(kt + (long)s0*DDIM + l*4);
      float d0 = qv.x*k0.x + qv.y*k0.y + qv.z*k0.z + qv.w*k0.w;
      d0 += __shfl_xor(d0, 1, 64);
      d0 += __shfl_xor(d0, 2, 64);
      d0 += __shfl_xor(d0, 4, 64);
      if (sub == 0) Et[(long)p*4 + hd] = __expf(d0);
    }
  }
}

// single-type version (pre-offset pointers)
__global__ __launch_bounds__(256) void hgt_score1_k(
    const int* __restrict__ rp, const int* __restrict__ srcs,
    const bfraw* __restrict__ qb, const bfraw* __restrict__ kt,
    float* __restrict__ E)
{
  int node = blockIdx.x*8 + (threadIdx.x >> 5);
  int l = threadIdx.x & 31;
  int hd = l >> 3, sub = l & 7;
  float4 qv = ld_bf4(qb + (long)node*DDIM + l*4);
  int beg = rp[node], end = rp[node+1];
  int p = beg;
  for (; p+1 < end; p += 2){
    int s0 = srcs[p], s1 = srcs[p+1];
    float4 k0 = ld_bf4(kt + (long)s0*DDIM + l*4);
    float4 k1 = ld_bf4(kt + (long)s1*DDIM + l*4);
    float d0 = qv.x*k0.x + qv.y*k0.y + qv.z*k0.z + qv.w*k0.w;
    float d1 = qv.x*k1.x + qv.y*k1.y + qv.z*k1.z + qv.w*k1.w;
    d0 += __shfl_xor(d0, 1, 64);  d1 += __shfl_xor(d1, 1, 64);
    d0 += __shfl_xor(d0, 2, 64);  d1 += __shfl_xor(d1, 2, 64);
    d0 += __shfl_xor(d0, 4, 64);  d1 += __shfl_xor(d1, 4, 64);
    if (sub == 0){
      E[(long)p*4 + hd]     = __expf(d0);
      E[(long)(p+1)*4 + hd] = __expf(d1);
    }
  }
  if (p < end){
    int s0 = srcs[p];
    float4 k0 = ld_bf4(kt + (long)s0*DDIM + l*4);
    float d0 = qv.x*k0.x + qv.y*k0.y + qv.z*k0.z + qv.w*k0.w;
    d0 += __shfl_xor(d0, 1, 64);
    d0 += __shfl_xor(d0, 2, 64);
    d0 += __shfl_xor(d0, 4, 64);
    if (sub == 0) E[(long)p*4 + hd] = __expf(d0);
  }
}

// ---------------- HGT fused acc: 3 types, dual chains, gelu finalize -> bf16 --------
__global__ __launch_bounds__(256) void hgt_acc_fused_k(
    const int* __restrict__ rp, const int* __restrict__ srcs,
    const float* __restrict__ E, const bfraw* __restrict__ V0,
    const bfraw* __restrict__ V1, const bfraw* __restrict__ V2,
    bfraw* __restrict__ out)
{
  int node = blockIdx.x*8 + (threadIdx.x >> 5);
  int l = threadIdx.x & 31;
  int hd = l >> 3;
  float axA=0.f, ayA=0.f, azA=0.f, awA=0.f, lsA=0.f;
  float axB=0.f, ayB=0.f, azB=0.f, awB=0.f, lsB=0.f;
  const bfraw* Vs[3] = {V0, V1, V2};
  #pragma unroll
  for (int t=0; t<3; t++){
    const bfraw* Vt = Vs[t];
    const float* Ep = E + (long)t*NEDGE*4;
    const int* sp = srcs + (long)t*NEDGE;
    int beg = rp[t*(NN+1) + node], end = rp[t*(NN+1) + node + 1];
    int p = beg;
    for (; p+1 < end; p += 2){
      int s0 = sp[p], s1 = sp[p+1];
      float e0 = Ep[(long)p*4 + hd];
      float e1 = Ep[(long)(p+1)*4 + hd];
      float4 v0 = ld_bf4(Vt + (long)s0*DDIM + l*4);
      float4 v1 = ld_bf4(Vt + (long)s1*DDIM + l*4);
      axA += e0*v0.x; ayA += e0*v0.y; azA += e0*v0.z; awA += e0*v0.w; lsA += e0;
      axB += e1*v1.x; ayB += e1*v1.y; azB += e1*v1.z; awB += e1*v1.w; lsB += e1;
    }
    if (p < end){
      int s0 = sp[p];
      float e0 = Ep[(long)p*4 + hd];
      float4 v0 = ld_bf4(Vt + (long)s0*DDIM + l*4);
      axA += e0*v0.x; ayA += e0*v0.y; azA += e0*v0.z; awA += e0*v0.w; lsA += e0;
    }
  }
  float lsum = lsA + lsB;
  float inv = (lsum > 0.f) ? 1.f/lsum : 0.f;
  float o0 = gelu_f((axA+axB)*inv), o1 = gelu_f((ayA+ayB)*inv);
  float o2 = gelu_f((azA+azB)*inv), o3 = gelu_f((awA+awB)*inv);
  unsigned int lo = ((unsigned int)f2bf(o1) << 16) | f2bf(o0);
  unsigned int hi = ((unsigned int)f2bf(o3) << 16) | f2bf(o2);
  *reinterpret_cast<uint2*>(out + (long)node*DDIM + l*4) = make_uint2(lo, hi);
}

// ---------------- FiLM ----------------
__global__ void film1_k(const float* __restrict__ z, const float* __restrict__ w1,
                        const float* __restrict__ b1, float* __restrict__ f1)
{
  int idx = blockIdx.x*256 + threadIdx.x;
  if (idx >= NGRAPH*256) return;
  int j = idx & 255, b = idx >> 8;
  const float* zr = z + (long)b*DDIM;
  float s = b1[j];
  for (int k=0;k<DDIM;k++) s += zr[k] * w1[(long)k*256 + j];
  f1[idx] = gelu_f(s);
}

__global__ void film2_k(const float* __restrict__ f1, const float* __restrict__ w2,
                        const float* __restrict__ b2, float* __restrict__ gb)
{
  int idx = blockIdx.x*256 + threadIdx.x;
  if (idx >= NGRAPH*256) return;
  int j = idx & 255, b = idx >> 8;
  const float* fr = f1 + (long)b*256;
  float s = b2[j];
  for (int k=0;k<256;k++) s += fr[k] * w2[(long)k*256 + j];
  gb[idx] = 0.1f*tanhf(s);                       // pre-apply 0.1*tanh for epilogue
}

// ---------------- host ----------------
extern "C" void kernel_launch(void* const* d_in, const int* in_sizes, int n_in,
                              void* d_out, int out_size, void* d_ws, size_t ws_size,
                              hipStream_t stream)
{
  (void)in_sizes; (void)n_in; (void)out_size; (void)ws_size;
  const float* x_cell = (const float*)d_in[0];
  const float* x_emb  = (const float*)d_in[1];
  const float* z_h    = (const float*)d_in[2];
  const int*   ei     = (const int*)d_in[3];
  const float* gw[2]  = {(const float*)d_in[4],  (const float*)d_in[8]};
  const float* gas[2] = {(const float*)d_in[5],  (const float*)d_in[9]};
  const float* gad[2] = {(const float*)d_in[6],  (const float*)d_in[10]};
  const float* gbi[2] = {(const float*)d_in[7],  (const float*)d_in[11]};
  const float* norm1  = (const float*)d_in[12];
  const float* norm2  = (const float*)d_in[13];
  const float* norm3  = (const float*)d_in[14];
  const float* kw = (const float*)d_in[15]; const float* kb = (const float*)d_in[16];
  const float* qw = (const float*)d_in[17]; const float* qb = (const float*)d_in[18];
  const float* vw = (const float*)d_in[19]; const float* vb = (const float*)d_in[20];
  const float* relk = (const float*)d_in[21];
  const float* relv = (const float*)d_in[22];
  const float* relp = (const float*)d_in[23];
  const float* aw = (const float*)d_in[24]; const float* ab = (const float*)d_in[25];
  const float* skip = (const float*)d_in[26];
  const float* injw = (const float*)d_in[27]; const float* injb = (const float*)d_in[28];
  const float* fw1 = (const float*)d_in[29]; const float* fb1 = (const float*)d_in[30];
  const float* fw2 = (const float*)d_in[31]; const float* fb2 = (const float*)d_in[32];

  const long ND = (long)NN*DDIM;
  float* X    = (float*)d_ws;                    // x1 / x2 (f32)
  float* K    = X + ND;                          // 2x bf16 buffers
  bfraw* Xb   = (bfraw*)(K + ND);                // bf16 GEMM A; later HGT attn out
  bfraw* Hb   = Xb + ND;                         // bf16: h0 / kt0,kt2 / vt0
  float* Sbuf = (float*)(Hb + ND);               // GAT SS [T][N][8] | HGT E [3E][4]
  float* sA   = Sbuf + (long)NTYPE*NEDGE*4;      // spare
  float* sB   = sA + (long)NN*4;                 // spare
  float* WkE  = sB + (long)NN*4;
  float* bkE  = WkE + (long)NTYPE*DDIM*DDIM;
  float* WvE  = bkE + (long)NTYPE*DDIM;
  float* bvE  = WvE + (long)NTYPE*DDIM*DDIM;
  bfraw* Pswz = (bfraw*)(bvE + (long)NTYPE*DDIM);   // 2 layers x 4096 bf16
  bfraw* Wall = Pswz + (long)2*4096;                // 15 swizzled bf16 weights
  float* f1b  = (float*)(Wall + (long)15*16384);
  float* gbb  = f1b + (long)NGRAPH*256;
  int*   deg  = (int*)(gbb + (long)NGRAPH*256);  // 3N (reused as cnt)
  int*   rp   = deg + (long)NTYPE*NN;            // 3(N+1)
  int*   srcs = rp  + (long)NTYPE*(NN+1);        // 3E
  int*   csum = srcs + (long)NTYPE*NEDGE;        // 192

  bfraw* Kb0 = (bfraw*)K;                        // K as 2 bf16 buffers
  bfraw* Kb1 = Kb0 + ND;

  const dim3 b256(256);
  float* NF = nullptr;
  bfraw* NB = nullptr; (void)NB; (void)sA; (void)sB;

  // ---------- CSR build ----------
  fill_k<<<256, b256, 0, stream>>>((float*)deg, 0.f, NTYPE*NN);
  hist_k<<<(NTYPE*NEDGE)/256, b256, 0, stream>>>(ei, deg);
  scan_a_k<<<dim3(64, NTYPE), b256, 0, stream>>>(deg, rp, csum);
  scan_b_k<<<NTYPE, 64, 0, stream>>>(csum);
  scan_c_k<<<dim3(64, NTYPE), b256, 0, stream>>>(rp, csum);
  fill_k<<<256, b256, 0, stream>>>((float*)deg, 0.f, NTYPE*NN);   // cnt
  scatter_k<<<(NTYPE*NEDGE)/256, b256, 0, stream>>>(ei, rp, deg, srcs);

  // ---------- weight prep ----------
  fold_k<<<(NTYPE*DDIM*DDIM)/256, b256, 0, stream>>>(kw, kb, relk, relp, WkE, bkE);
  fold_k<<<(NTYPE*DDIM*DDIM)/256, b256, 0, stream>>>(vw, vb, relv, NF, WvE, bvE);
  wswz_k<<<dim3(64, 15), b256, 0, stream>>>(
      gw[0], gw[0]+16384, gw[0]+32768,
      gw[1], gw[1]+16384, gw[1]+32768,
      qw, WkE, WvE, aw, injw, Wall);
  gatproj_k<<<16, b256, 0, stream>>>(gw[0], gas[0], gad[0], Pswz);
  gatproj_k<<<16, b256, 0, stream>>>(gw[1], gas[1], gad[1], Pswz + 4096);

  // ---------- FiLM (independent, run early) ----------
  film1_k<<<(NGRAPH*256)/256, b256, 0, stream>>>(z_h, fw1, fb1, f1b);
  film2_k<<<(NGRAPH*256)/256, b256, 0, stream>>>(f1b, fw2, fb2, gbb);

  // ---------- GAT layers ----------
  for (int layer=0; layer<2; layer++){
    gemm3_k<<<NN/128, b256, 0, stream>>>(
        Xb, (layer==0) ? x_cell : NF,
        Wall + (long)(layer*3+0)*16384, Wall + (long)(layer*3+1)*16384,
        Wall + (long)(layer*3+2)*16384,
        NF, NF, NF,
        Hb, Kb0, Kb1,
        Pswz + (long)layer*4096, Sbuf);
    gat_fused_k<<<NN/8, b256, 0, stream>>>(
        rp, srcs, Hb, Kb0, Kb1, Sbuf, gbi[layer],
        (layer==0) ? x_cell : X, (layer==0) ? norm1 : norm2, X, Xb);
  }

  // ---------- HGT ----------
  // q (bf16) -> Kb0, kt0 -> Hb, kt1 -> Kb1, reading A once
  gemm3_k<<<NN/128, b256, 0, stream>>>(
      Xb, NF, Wall + (long)6*16384, Wall + (long)7*16384, Wall + (long)8*16384,
      qb, bkE, bkE + DDIM,
      Kb0, Hb, Kb1, nullptr, nullptr);
  hgt_score2_k<<<NN/8, b256, 0, stream>>>(rp, srcs, Kb0, Hb, Kb1, Sbuf);
  gemm_out_k<<<NN/128, b256, 0, stream>>>(Xb, Wall + (long)9*16384, bkE + 2*DDIM, Hb);
  hgt_score1_k<<<NN/8, b256, 0, stream>>>(rp + 2*(NN+1), srcs + 2*NEDGE, Kb0, Hb,
      Sbuf + (long)2*NEDGE*4);
  // vt0..2 -> Hb, Kb0 (q dead), Kb1 (kt1 dead), reading A once
  gemm3_k<<<NN/128, b256, 0, stream>>>(
      Xb, NF, Wall + (long)10*16384, Wall + (long)11*16384, Wall + (long)12*16384,
      bvE, bvE + DDIM, bvE + 2*DDIM,
      Hb, Kb0, Kb1, nullptr, nullptr);
  hgt_acc_fused_k<<<NN/8, b256, 0, stream>>>(rp, srcs, Sbuf, Hb, Kb0, Kb1, Xb);
  // fused: GEMM(attn@aw) + res3 + GEMM(x_emb@injw) + FiLM -> out (x3 never stored)
  gemm_r3film_k<<<NN/128, b256, 0, stream>>>(
      Xb, Wall + (long)13*16384, ab, X, norm3, skip,
      x_emb, Wall + (long)14*16384, injb, gbb, (float*)d_out);
}